// Round 10
// baseline (456.987 us; speedup 1.0000x reference)
//
#include <hip/hip_runtime.h>
#include <hip/hip_bf16.h>

#define KDIM 512
#define NDIM 512
#define ATT  196
#define NB   1024

typedef __attribute__((ext_vector_type(8))) short bf16x8;
typedef __attribute__((ext_vector_type(8))) unsigned short ushort8;
typedef __attribute__((ext_vector_type(4))) float f32x4;

typedef const __attribute__((address_space(1))) unsigned int gas_uint;
typedef __attribute__((address_space(3))) unsigned int las_uint;

__device__ __forceinline__ void gload16(const void* g, void* l) {
    __builtin_amdgcn_global_load_lds((gas_uint*)g, (las_uint*)l, 16, 0, 0);
}

__device__ __forceinline__ float fast_tanh(float x) {
    x = fminf(15.f, fmaxf(-15.f, x));
    float t = __expf(2.f * x);
    return (t - 1.f) / (t + 1.f);
}

__device__ __forceinline__ unsigned short f2bf(float x) {
    union { float f; unsigned u; } v; v.f = x;
    unsigned r = v.u + 0x7FFF + ((v.u >> 16) & 1);   // RNE
    return (unsigned short)(r >> 16);
}

__device__ __forceinline__ unsigned pk2(float a, float b) {
    __hip_bfloat162 h = __float22bfloat162_rn(float2{a, b});
    union { __hip_bfloat162 h2; unsigned u; } c; c.h2 = h;
    return c.u;
}

// ---------------------------------------------------------------------------
// Transpose+cast 6 weights: W[k][n] f32 -> Wt[n][k] bf16 ([n][k] row-major).
// ---------------------------------------------------------------------------
__global__ __launch_bounds__(256) void prep_weights(
        const float* __restrict__ W0, const float* __restrict__ W1,
        const float* __restrict__ W2, const float* __restrict__ W3,
        const float* __restrict__ W4, const float* __restrict__ W5,
        unsigned short* __restrict__ Wt) {
    int w = blockIdx.x >> 6;
    int t = blockIdx.x & 63;
    int k0 = (t >> 3) << 6, n0 = (t & 7) << 6;
    const float* W = (w == 0) ? W0 : (w == 1) ? W1 : (w == 2) ? W2 :
                     (w == 3) ? W3 : (w == 4) ? W4 : W5;
    __shared__ float tile[64][65];
    int tid = threadIdx.x;
    int nc = tid & 15, kr = tid >> 4;
#pragma unroll
    for (int i = 0; i < 4; ++i) {
        int k = kr + i * 16;
        float4 v = *(const float4*)&W[(size_t)(k0 + k) * NDIM + n0 + nc * 4];
        tile[k][nc * 4 + 0] = v.x; tile[k][nc * 4 + 1] = v.y;
        tile[k][nc * 4 + 2] = v.z; tile[k][nc * 4 + 3] = v.w;
    }
    __syncthreads();
    int n = tid >> 2, ks = tid & 3;
    ushort8 v0, v1;
#pragma unroll
    for (int j = 0; j < 8; ++j) v0[j] = f2bf(tile[ks * 16 + j][n]);
#pragma unroll
    for (int j = 0; j < 8; ++j) v1[j] = f2bf(tile[ks * 16 + 8 + j][n]);
    size_t base = ((size_t)w << 18) + (size_t)(n0 + n) * KDIM + k0 + ks * 16;
    *(ushort8*)&Wt[base] = v0;
    *(ushort8*)&Wt[base + 8] = v1;
}

// ---------------------------------------------------------------------------
// Small GEMM: out = act(A[1024,512] @ Wt^T + bias). BM=64, BN=128,
// 256 thr = 4 waves (2Mx2N), wave 32x64. Two ops batched via blockIdx.y.
// act: 0=relu 1=tanh 2=none
// ---------------------------------------------------------------------------
__global__ __launch_bounds__(256) void gemm64(
        const float* __restrict__ A0, const unsigned short* __restrict__ W0,
        const float* __restrict__ bia0, float* __restrict__ O0, int act0,
        const float* __restrict__ A1, const unsigned short* __restrict__ W1,
        const float* __restrict__ bia1, float* __restrict__ O1, int act1) {
    const int op = blockIdx.y;
    const float* A = op ? A1 : A0;
    const unsigned short* Bt = op ? W1 : W0;
    const float* bias = op ? bia1 : bia0;
    float* out = op ? O1 : O0;
    const int act = op ? act1 : act0;

    __shared__ unsigned short A_lds[2][64 * 32];
    __shared__ unsigned short B_lds[2][128 * 32];

    const int tid = threadIdx.x;
    const int gm0 = (blockIdx.x >> 2) * 64, gn0 = (blockIdx.x & 3) * 128;
    const int wid = tid >> 6, lane = tid & 63;
    const int wm = wid >> 1, wn = wid & 1;
    const int lr = lane & 15, lk = lane >> 4;

    const int arow = tid >> 2, akc = tid & 3;
    const float* aptr = A + (size_t)(gm0 + arow) * KDIM + akc * 8;
    const int aoff = arow * 32 + ((akc ^ ((arow >> 1) & 3)) << 3);

    auto stageB = [&](int kt, int buf) {
#pragma unroll
        for (int j = 0; j < 2; ++j) {
            int c = tid + j * 256;
            int col = c >> 2, slot = c & 3;
            const unsigned short* src = Bt + (size_t)(gn0 + col) * KDIM +
                                        ((slot ^ ((col >> 1) & 3)) << 3) + kt * 32;
            gload16(src, &B_lds[buf][c * 8]);
        }
    };

    f32x4 acc[2][4] = {};

    {
        float4 x0 = *(const float4*)aptr;
        float4 x1 = *(const float4*)(aptr + 4);
        stageB(0, 0);
        uint4 p;
        p.x = pk2(x0.x, x0.y); p.y = pk2(x0.z, x0.w);
        p.z = pk2(x1.x, x1.y); p.w = pk2(x1.z, x1.w);
        *(uint4*)&A_lds[0][aoff] = p;
    }
    __syncthreads();

    const int swk = ((lk ^ ((lr >> 1) & 3)) << 3);
    for (int kt = 0; kt < 16; ++kt) {
        const int buf = kt & 1;
        float4 x0, x1;
        if (kt < 15) {
            const float* ap = aptr + (kt + 1) * 32;
            x0 = *(const float4*)ap;
            x1 = *(const float4*)(ap + 4);
            stageB(kt + 1, buf ^ 1);
        }
        bf16x8 af[2], bfr[4];
#pragma unroll
        for (int m = 0; m < 2; ++m)
            af[m] = *(const bf16x8*)&A_lds[buf][(wm * 32 + m * 16 + lr) * 32 + swk];
#pragma unroll
        for (int n = 0; n < 4; ++n)
            bfr[n] = *(const bf16x8*)&B_lds[buf][(wn * 64 + n * 16 + lr) * 32 + swk];
#pragma unroll
        for (int m = 0; m < 2; ++m)
#pragma unroll
            for (int n = 0; n < 4; ++n)
                acc[m][n] = __builtin_amdgcn_mfma_f32_16x16x32_bf16(af[m], bfr[n], acc[m][n], 0, 0, 0);
        if (kt < 15) {
            uint4 p;
            p.x = pk2(x0.x, x0.y); p.y = pk2(x0.z, x0.w);
            p.z = pk2(x1.x, x1.y); p.w = pk2(x1.z, x1.w);
            *(uint4*)&A_lds[buf ^ 1][aoff] = p;
        }
        __syncthreads();
    }

#pragma unroll
    for (int m = 0; m < 2; ++m)
#pragma unroll
        for (int n = 0; n < 4; ++n) {
            int col = gn0 + wn * 64 + n * 16 + lr;
            float bsv = bias[col];
#pragma unroll
            for (int r = 0; r < 4; ++r) {
                int row = gm0 + wm * 32 + m * 16 + lk * 4 + r;
                float v = acc[m][n][r] + bsv;
                if (act == 0) v = fmaxf(v, 0.f);
                else if (act == 1) v = fast_tanh(v);
                out[(size_t)row * NDIM + col] = v;
            }
        }
}

// ---------------------------------------------------------------------------
// Score GEMM, R10: R8 interior + T3/T4 counted-vmcnt 2-deep pipeline.
// BM=BN=128, BK=32, 256 thr (2Mx2N waves, 64x64/wave). 3 LDS buffer sets
// (A f32 16KB + B bf16 8KB each = 72KB -> 2 blocks/CU). Staging issued 2
// tiles ahead; each step tops with s_waitcnt vmcnt(6) (tile t's 6 loads are
// the oldest; the newest tile's 6 stay IN FLIGHT across the raw s_barrier).
// Cross-wave visibility: same-schedule + counted wait + barrier (m201).
// A staged as f32 (source-swizzled granules g^=(row&7)), consumer-side
// cvt_pk; B staged with source-baked swizzle. T5 setprio around MFMAs.
// Epilogue: per-row partial of sum_col tanh(acc+b_ctx+h_emb)*Walpha
// -> atomicAdd. Grid 6272 = 8 XCD x 196 mtiles x 4 nblk.
// ---------------------------------------------------------------------------
__launch_bounds__(256, 2)
__global__ void gemm_score(const float* __restrict__ A,
                           const unsigned short* __restrict__ Bt,
                           const float* __restrict__ b_ctx,
                           const float* __restrict__ h_emb,
                           const float* __restrict__ Walpha,
                           float* __restrict__ score) {
    __shared__ float A_f[3][128 * 32];             // 3 x 16 KB f32
    __shared__ unsigned short B_lds[3][128 * 32];  // 3 x 8 KB bf16
    __shared__ float ch_s[2][128];
    __shared__ float wa_s[128];
    __shared__ float s_red[2][128];

    const int tid  = threadIdx.x;
    const int bidx = blockIdx.x;
    const int xcd  = bidx & 7, u = bidx >> 3;
    const int mblk = xcd * 196 + (u >> 2), nblk = u & 3;
    const int gm0  = mblk * 128, gn0 = nblk * 128;

    const int wid = tid >> 6, lane = tid & 63;
    const int wm  = wid >> 1, wn = wid & 1;
    const int lr  = lane & 15, lk = lane >> 4;

    const int bb0 = gm0 / ATT;
    {
        int j = tid >> 7, cloc = tid & 127;
        int bb = bb0 + j; if (bb > NB - 1) bb = NB - 1;
        ch_s[j][cloc] = b_ctx[gn0 + cloc] + h_emb[(size_t)bb * NDIM + gn0 + cloc];
        if (tid < 128) wa_s[tid] = Walpha[gn0 + tid];
    }

    // A staging: granule c (16B of f32) -> row=c>>3, dest slot g=c&7 holds
    // source granule g^(row&7). 4 gload_lds per thread, LDS dest linear.
    const float* asrc[4];
#pragma unroll
    for (int i = 0; i < 4; ++i) {
        int c = tid + i * 256;
        int row = c >> 3, g = c & 7;
        asrc[i] = A + (size_t)(gm0 + row) * KDIM + ((g ^ (row & 7)) << 2);
    }
    auto stageA = [&](int kt, int buf) {
#pragma unroll
        for (int i = 0; i < 4; ++i)
            gload16(asrc[i] + kt * 32, &A_f[buf][(tid + i * 256) * 4]);
    };

    // B staging: chunk c -> col=c>>2, slot=c&3 holds src kc=slot^((col>>1)&3)
    const int c1 = tid + 256;
    const int bcol0 = tid >> 2, bk0 = (tid & 3) ^ ((bcol0 >> 1) & 3);
    const int bcol1 = c1 >> 2,  bk1 = (c1 & 3) ^ ((bcol1 >> 1) & 3);
    const unsigned short* bsrc0 = Bt + (size_t)(gn0 + bcol0) * KDIM + bk0 * 8;
    const unsigned short* bsrc1 = Bt + (size_t)(gn0 + bcol1) * KDIM + bk1 * 8;
    auto stageB = [&](int kt, int buf) {
        gload16(bsrc0 + kt * 32, &B_lds[buf][tid * 8]);
        gload16(bsrc1 + kt * 32, &B_lds[buf][c1 * 8]);
    };

    f32x4 acc[4][4] = {};
    const int swk = ((lk ^ ((lr >> 1) & 3)) << 3);
    const int arw = lr & 7;              // frag row & 7 (wm*64, m*16 are 0 mod 8)
    const int as0 = (lk * 2) ^ arw;
    const int as1 = (lk * 2 + 1) ^ arw;

    // ---- prologue: tiles 0 and 1 in flight (12 ops) ----
    stageA(0, 0); stageB(0, 0);
    stageA(1, 1); stageB(1, 1);

    int cur = 0;
#pragma unroll 1
    for (int kt = 0; kt < 16; ++kt) {
        // top-of-step: wait for tile kt only (newest 6 = tile kt+1 stay in
        // flight across the barrier); last step drains fully.
        if (kt < 15)
            asm volatile("s_waitcnt vmcnt(6)" ::: "memory");
        else
            asm volatile("s_waitcnt vmcnt(0)" ::: "memory");
        __builtin_amdgcn_sched_barrier(0);
        __builtin_amdgcn_s_barrier();
        __builtin_amdgcn_sched_barrier(0);

        // issue staging for kt+2 into buffer (cur+2)%3 (its readers finished
        // in step kt-1, guaranteed by the barrier just crossed)
        if (kt + 2 < 16) {
            int nb = cur + 2; if (nb >= 3) nb -= 3;
            stageA(kt + 2, nb);
            stageB(kt + 2, nb);
        }

        bf16x8 af[4], bfr[4];
#pragma unroll
        for (int n = 0; n < 4; ++n)
            bfr[n] = *(const bf16x8*)&B_lds[cur][(wn * 64 + n * 16 + lr) * 32 + swk];
#pragma unroll
        for (int m = 0; m < 4; ++m) {
            const int rbase = (wm * 64 + m * 16 + lr) * 32;
            float4 fa = *(const float4*)&A_f[cur][rbase + as0 * 4];
            float4 fb = *(const float4*)&A_f[cur][rbase + as1 * 4];
            uint4 p;
            p.x = pk2(fa.x, fa.y); p.y = pk2(fa.z, fa.w);
            p.z = pk2(fb.x, fb.y); p.w = pk2(fb.z, fb.w);
            union { uint4 u; bf16x8 v; } cc; cc.u = p;
            af[m] = cc.v;
        }
        __builtin_amdgcn_s_setprio(1);
#pragma unroll
        for (int m = 0; m < 4; ++m)
#pragma unroll
            for (int n = 0; n < 4; ++n)
                acc[m][n] = __builtin_amdgcn_mfma_f32_16x16x32_bf16(af[m], bfr[n], acc[m][n], 0, 0, 0);
        __builtin_amdgcn_s_setprio(0);

        cur = (cur == 2) ? 0 : cur + 1;
    }
    __syncthreads();

    // ---- epilogue: per-row partial score ----
    const int bsplit = (bb0 + 1) * ATT;
#pragma unroll
    for (int m = 0; m < 4; ++m) {
#pragma unroll
        for (int r = 0; r < 4; ++r) {
            int rloc = wm * 64 + m * 16 + lk * 4 + r;
            int rg = gm0 + rloc;
            int sel = (rg >= bsplit) ? 1 : 0;
            float sum = 0.f;
#pragma unroll
            for (int n = 0; n < 4; ++n) {
                int cloc = wn * 64 + n * 16 + lr;
                sum += fast_tanh(acc[m][n][r] + ch_s[sel][cloc]) * wa_s[cloc];
            }
            sum += __shfl_xor(sum, 1);
            sum += __shfl_xor(sum, 2);
            sum += __shfl_xor(sum, 4);
            sum += __shfl_xor(sum, 8);
            if (lr == 0) s_red[wn][rloc] = sum;
        }
    }
    __syncthreads();
    if (tid < 128) {
        float tot = s_red[0][tid] + s_red[1][tid];
        int rg = gm0 + tid;
        int sel = (rg >= bsplit) ? 1 : 0;
        int bb = bb0 + sel;
        atomicAdd(&score[(size_t)bb * 197 + (rg - bb * ATT) + 1], tot);
    }
}

// ---------------------------------------------------------------------------
// Per-batch: sentinel score (pos 0) from sent_emb+h_emb, softmax over 197,
// atten_out[b,:] = al0*sent_lin + sum_s al[s+1]*att[b,s,:] + h_lin
// ---------------------------------------------------------------------------
__global__ __launch_bounds__(256) void softmax_chat(
        const float* __restrict__ score, const float* __restrict__ sent_emb,
        const float* __restrict__ h_emb, const float* __restrict__ Walpha,
        const float* __restrict__ sent_lin, const float* __restrict__ h_lin,
        const float* __restrict__ att, float* __restrict__ atten_out) {
    int b = blockIdx.x, tid = threadIdx.x;
    __shared__ float al[200];
    __shared__ float r4[4];

    float2 se = ((const float2*)(sent_emb + (size_t)b * NDIM))[tid];
    float2 he = ((const float2*)(h_emb + (size_t)b * NDIM))[tid];
    float2 wa = ((const float2*)Walpha)[tid];
    float val = fast_tanh(se.x + he.x) * wa.x + fast_tanh(se.y + he.y) * wa.y;
#pragma unroll
    for (int o = 32; o; o >>= 1) val += __shfl_xor(val, o);
    if ((tid & 63) == 0) r4[tid >> 6] = val;
    __syncthreads();
    float ssent = r4[0] + r4[1] + r4[2] + r4[3];
    __syncthreads();

    float v = -1e30f;
    if (tid < 197) v = (tid == 0) ? ssent : score[(size_t)b * 197 + tid];
    float m = v;
#pragma unroll
    for (int o = 32; o; o >>= 1) m = fmaxf(m, __shfl_xor(m, o));
    if ((tid & 63) == 0) r4[tid >> 6] = m;
    __syncthreads();
    m = fmaxf(fmaxf(r4[0], r4[1]), fmaxf(r4[2], r4[3]));
    __syncthreads();
    float e = (tid < 197) ? __expf(v - m) : 0.f;
    float s = e;
#pragma unroll
    for (int o = 32; o; o >>= 1) s += __shfl_xor(s, o);
    if ((tid & 63) == 0) r4[tid >> 6] = s;
    __syncthreads();
    s = r4[0] + r4[1] + r4[2] + r4[3];
    if (tid < 197) al[tid] = e / s;
    __syncthreads();

    const float2* af = (const float2*)(att + (size_t)b * ATT * KDIM);
    float2 a0 = ((const float2*)(sent_lin + (size_t)b * KDIM))[tid];
    float w0 = al[0];
    float2 accv; accv.x = w0 * a0.x; accv.y = w0 * a0.y;
#pragma unroll 14
    for (int ss = 0; ss < ATT; ++ss) {
        float w = al[ss + 1];
        float2 x = af[(size_t)ss * 256 + tid];
        accv.x += w * x.x; accv.y += w * x.y;
    }
    float2 hl = ((const float2*)(h_lin + (size_t)b * KDIM))[tid];
    accv.x += hl.x; accv.y += hl.y;
    ((float2*)(atten_out + (size_t)b * KDIM))[tid] = accv;
}

// ---------------------------------------------------------------------------
extern "C" void kernel_launch(void* const* d_in, const int* in_sizes, int n_in,
                              void* d_out, int out_size, void* d_ws, size_t ws_size,
                              hipStream_t stream) {
    const float* h     = (const float*)d_in[0];
    const float* sent  = (const float*)d_in[1];
    const float* att   = (const float*)d_in[2];
    const float* W_ctx = (const float*)d_in[3];
    const float* b_ctx = (const float*)d_in[4];
    const float* W_sl  = (const float*)d_in[5];
    const float* b_sl  = (const float*)d_in[6];
    const float* W_se  = (const float*)d_in[7];
    const float* b_se  = (const float*)d_in[8];
    const float* W_hl  = (const float*)d_in[9];
    const float* b_hl  = (const float*)d_in[10];
    const float* W_he  = (const float*)d_in[11];
    const float* b_he  = (const float*)d_in[12];
    const float* W_al  = (const float*)d_in[13];
    // d_in[14] = b_alpha: constant across positions, cancels in softmax
    const float* W_a2h = (const float*)d_in[15];
    const float* b_a2h = (const float*)d_in[16];
    float* out = (float*)d_out;

    char* ws = (char*)d_ws;
    unsigned short* Wt = (unsigned short*)ws;                 // 6 * 512KB bf16 = 3MB
    float* sent_lin = (float*)(ws + 6u * 512 * 1024);
    float* h_lin    = sent_lin + (size_t)NB * 512;
    float* h_emb    = h_lin    + (size_t)NB * 512;
    float* sent_emb = h_emb    + (size_t)NB * 512;
    float* scorebuf = sent_emb + (size_t)NB * 512;            // 1024*197
    float* atten    = scorebuf + (size_t)NB * 197;

    const size_t WSZ = 512 * 512;  // ushorts per weight
    // Wt order: 0=W_sl 1=W_hl 2=W_he 3=W_ctx 4=W_a2h 5=W_se
    prep_weights<<<384, 256, 0, stream>>>(W_sl, W_hl, W_he, W_ctx, W_a2h, W_se, Wt);
    hipMemsetAsync(scorebuf, 0, (size_t)NB * 197 * sizeof(float), stream);

    // sent_lin = relu(sent@W_sl+b_sl); h_lin = tanh(h@W_hl+b_hl)
    gemm64<<<dim3(64, 2), 256, 0, stream>>>(
        sent, Wt + 0 * WSZ, b_sl, sent_lin, 0,
        h,    Wt + 1 * WSZ, b_hl, h_lin,    1);
    // h_emb = h_lin@W_he+b_he; sent_emb = sent_lin@W_se+b_se
    gemm64<<<dim3(64, 2), 256, 0, stream>>>(
        h_lin,    Wt + 2 * WSZ, b_he, h_emb,    2,
        sent_lin, Wt + 5 * WSZ, b_se, sent_emb, 2);

    // visual scores -> scorebuf[b*197 + 1 + s]
    gemm_score<<<6272, 256, 0, stream>>>(att, Wt + 3 * WSZ, b_ctx, h_emb, W_al, scorebuf);

    softmax_chat<<<NB, 256, 0, stream>>>(scorebuf, sent_emb, h_emb, W_al,
                                         sent_lin, h_lin, att, atten);

    // out = tanh(atten@W_a2h + b_a2h)
    gemm64<<<dim3(64, 1), 256, 0, stream>>>(
        atten, Wt + 4 * WSZ, b_a2h, out, 1,
        atten, Wt + 4 * WSZ, b_a2h, out, 1);
}

// Round 12
// 381.356 us; speedup vs baseline: 1.1983x; 1.1983x over previous
//
#include <hip/hip_runtime.h>
#include <hip/hip_bf16.h>

#define KDIM 512
#define NDIM 512
#define ATT  196
#define NB   1024

typedef __attribute__((ext_vector_type(8))) short bf16x8;
typedef __attribute__((ext_vector_type(8))) unsigned short ushort8;
typedef __attribute__((ext_vector_type(4))) float f32x4;

typedef const __attribute__((address_space(1))) unsigned int gas_uint;
typedef __attribute__((address_space(3))) unsigned int las_uint;

__device__ __forceinline__ void gload16(const void* g, void* l) {
    __builtin_amdgcn_global_load_lds((gas_uint*)g, (las_uint*)l, 16, 0, 0);
}

__device__ __forceinline__ float fast_tanh(float x) {
    x = fminf(15.f, fmaxf(-15.f, x));
    float t = __expf(2.f * x);
    return (t - 1.f) / (t + 1.f);
}

__device__ __forceinline__ unsigned short f2bf(float x) {
    union { float f; unsigned u; } v; v.f = x;
    unsigned r = v.u + 0x7FFF + ((v.u >> 16) & 1);   // RNE
    return (unsigned short)(r >> 16);
}

__device__ __forceinline__ unsigned pk2(float a, float b) {
    __hip_bfloat162 h = __float22bfloat162_rn(float2{a, b});
    union { __hip_bfloat162 h2; unsigned u; } c; c.h2 = h;
    return c.u;
}

// ---------------------------------------------------------------------------
// Transpose+cast 6 weights: W[k][n] f32 -> Wt[n][k] bf16 ([n][k] row-major).
// ---------------------------------------------------------------------------
__global__ __launch_bounds__(256) void prep_weights(
        const float* __restrict__ W0, const float* __restrict__ W1,
        const float* __restrict__ W2, const float* __restrict__ W3,
        const float* __restrict__ W4, const float* __restrict__ W5,
        unsigned short* __restrict__ Wt) {
    int w = blockIdx.x >> 6;
    int t = blockIdx.x & 63;
    int k0 = (t >> 3) << 6, n0 = (t & 7) << 6;
    const float* W = (w == 0) ? W0 : (w == 1) ? W1 : (w == 2) ? W2 :
                     (w == 3) ? W3 : (w == 4) ? W4 : W5;
    __shared__ float tile[64][65];
    int tid = threadIdx.x;
    int nc = tid & 15, kr = tid >> 4;
#pragma unroll
    for (int i = 0; i < 4; ++i) {
        int k = kr + i * 16;
        float4 v = *(const float4*)&W[(size_t)(k0 + k) * NDIM + n0 + nc * 4];
        tile[k][nc * 4 + 0] = v.x; tile[k][nc * 4 + 1] = v.y;
        tile[k][nc * 4 + 2] = v.z; tile[k][nc * 4 + 3] = v.w;
    }
    __syncthreads();
    int n = tid >> 2, ks = tid & 3;
    ushort8 v0, v1;
#pragma unroll
    for (int j = 0; j < 8; ++j) v0[j] = f2bf(tile[ks * 16 + j][n]);
#pragma unroll
    for (int j = 0; j < 8; ++j) v1[j] = f2bf(tile[ks * 16 + 8 + j][n]);
    size_t base = ((size_t)w << 18) + (size_t)(n0 + n) * KDIM + k0 + ks * 16;
    *(ushort8*)&Wt[base] = v0;
    *(ushort8*)&Wt[base + 8] = v1;
}

// ---------------------------------------------------------------------------
// Small GEMM: out = act(A[1024,512] @ Wt^T + bias). BM=64, BN=128,
// 256 thr = 4 waves (2Mx2N), wave 32x64. Two ops batched via blockIdx.y.
// act: 0=relu 1=tanh 2=none
// ---------------------------------------------------------------------------
__global__ __launch_bounds__(256) void gemm64(
        const float* __restrict__ A0, const unsigned short* __restrict__ W0,
        const float* __restrict__ bia0, float* __restrict__ O0, int act0,
        const float* __restrict__ A1, const unsigned short* __restrict__ W1,
        const float* __restrict__ bia1, float* __restrict__ O1, int act1) {
    const int op = blockIdx.y;
    const float* A = op ? A1 : A0;
    const unsigned short* Bt = op ? W1 : W0;
    const float* bias = op ? bia1 : bia0;
    float* out = op ? O1 : O0;
    const int act = op ? act1 : act0;

    __shared__ unsigned short A_lds[2][64 * 32];
    __shared__ unsigned short B_lds[2][128 * 32];

    const int tid = threadIdx.x;
    const int gm0 = (blockIdx.x >> 2) * 64, gn0 = (blockIdx.x & 3) * 128;
    const int wid = tid >> 6, lane = tid & 63;
    const int wm = wid >> 1, wn = wid & 1;
    const int lr = lane & 15, lk = lane >> 4;

    const int arow = tid >> 2, akc = tid & 3;
    const float* aptr = A + (size_t)(gm0 + arow) * KDIM + akc * 8;
    const int aoff = arow * 32 + ((akc ^ ((arow >> 1) & 3)) << 3);

    auto stageB = [&](int kt, int buf) {
#pragma unroll
        for (int j = 0; j < 2; ++j) {
            int c = tid + j * 256;
            int col = c >> 2, slot = c & 3;
            const unsigned short* src = Bt + (size_t)(gn0 + col) * KDIM +
                                        ((slot ^ ((col >> 1) & 3)) << 3) + kt * 32;
            gload16(src, &B_lds[buf][c * 8]);
        }
    };

    f32x4 acc[2][4] = {};

    {
        float4 x0 = *(const float4*)aptr;
        float4 x1 = *(const float4*)(aptr + 4);
        stageB(0, 0);
        uint4 p;
        p.x = pk2(x0.x, x0.y); p.y = pk2(x0.z, x0.w);
        p.z = pk2(x1.x, x1.y); p.w = pk2(x1.z, x1.w);
        *(uint4*)&A_lds[0][aoff] = p;
    }
    __syncthreads();

    const int swk = ((lk ^ ((lr >> 1) & 3)) << 3);
    for (int kt = 0; kt < 16; ++kt) {
        const int buf = kt & 1;
        float4 x0, x1;
        if (kt < 15) {
            const float* ap = aptr + (kt + 1) * 32;
            x0 = *(const float4*)ap;
            x1 = *(const float4*)(ap + 4);
            stageB(kt + 1, buf ^ 1);
        }
        bf16x8 af[2], bfr[4];
#pragma unroll
        for (int m = 0; m < 2; ++m)
            af[m] = *(const bf16x8*)&A_lds[buf][(wm * 32 + m * 16 + lr) * 32 + swk];
#pragma unroll
        for (int n = 0; n < 4; ++n)
            bfr[n] = *(const bf16x8*)&B_lds[buf][(wn * 64 + n * 16 + lr) * 32 + swk];
#pragma unroll
        for (int m = 0; m < 2; ++m)
#pragma unroll
            for (int n = 0; n < 4; ++n)
                acc[m][n] = __builtin_amdgcn_mfma_f32_16x16x32_bf16(af[m], bfr[n], acc[m][n], 0, 0, 0);
        if (kt < 15) {
            uint4 p;
            p.x = pk2(x0.x, x0.y); p.y = pk2(x0.z, x0.w);
            p.z = pk2(x1.x, x1.y); p.w = pk2(x1.z, x1.w);
            *(uint4*)&A_lds[buf ^ 1][aoff] = p;
        }
        __syncthreads();
    }

#pragma unroll
    for (int m = 0; m < 2; ++m)
#pragma unroll
        for (int n = 0; n < 4; ++n) {
            int col = gn0 + wn * 64 + n * 16 + lr;
            float bsv = bias[col];
#pragma unroll
            for (int r = 0; r < 4; ++r) {
                int row = gm0 + wm * 32 + m * 16 + lk * 4 + r;
                float v = acc[m][n][r] + bsv;
                if (act == 0) v = fmaxf(v, 0.f);
                else if (act == 1) v = fast_tanh(v);
                out[(size_t)row * NDIM + col] = v;
            }
        }
}

// ---------------------------------------------------------------------------
// Score GEMM (R9 structure): BM=256, BN=128, 512 thr (8 waves, 4Mx2N, wave
// 64x64). A staged f32 via global_load_lds (source-swizzled granules
// g^=(row&7)), consumer-side cvt_pk; B via global_load_lds with source-baked
// swizzle. LDS exactly 80 KB -> 2 blocks/CU.
// R12 fix: owner-write of bf16 A-frags to attbf uses LINEAR source k-offsets
// (kt*16 + lk*4 unsigneds), and only wn==0 waves write (no duplicates).
// Epilogue handles up to 3 batch spans; atomicAdd partials into score.
// Grid 3136 = 8 XCD x 98 mtiles x 4 nblk.
// ---------------------------------------------------------------------------
__launch_bounds__(512, 4)
__global__ void gemm_score(const float* __restrict__ A,
                           const unsigned short* __restrict__ Bt,
                           const float* __restrict__ b_ctx,
                           const float* __restrict__ h_emb,
                           const float* __restrict__ Walpha,
                           float* __restrict__ score,
                           unsigned short* __restrict__ attbf) {
    __shared__ char smem[81920];
    float (*A_f)[256 * 32] = (float (*)[256 * 32])smem;                       // 2x32KB
    unsigned short (*B_lds)[128 * 32] = (unsigned short (*)[128 * 32])(smem + 65536); // 2x8KB
    // epilogue aliases (A_f region is dead after the K-loop's final barrier)
    float* ch_s = (float*)smem;            // [3][128]
    float* wa_s = (float*)(smem + 1536);   // [128]
    float* s_red = (float*)(smem + 2048);  // [2][256]

    const int tid  = threadIdx.x;
    const int bidx = blockIdx.x;
    const int xcd  = bidx & 7, u = bidx >> 3;
    const int mblk = xcd * 98 + (u >> 2), nblk = u & 3;
    const int gm0  = mblk * 256, gn0 = nblk * 128;

    const int wid = tid >> 6, lane = tid & 63;
    const int wm  = wid >> 1, wn = wid & 1;
    const int lr  = lane & 15, lk = lane >> 4;

    const bool wrbf = (attbf != nullptr) && (nblk == 0) && (wn == 0);

    // A staging: granule c (16B f32) -> row=c>>3, dest slot g=c&7 holds
    // source granule g^(row&7). 4 gload_lds/thread, LDS dest linear.
    const float* asrc[4];
#pragma unroll
    for (int i = 0; i < 4; ++i) {
        int c = tid + i * 512;
        int row = c >> 3, g = c & 7;
        asrc[i] = A + (size_t)(gm0 + row) * KDIM + ((g ^ (row & 7)) << 2);
    }
    auto stageA = [&](int kt, int buf) {
#pragma unroll
        for (int i = 0; i < 4; ++i)
            gload16(asrc[i] + kt * 32, &A_f[buf][(tid + i * 512) * 4]);
    };

    // B staging: chunk c=tid -> col=c>>2, slot=c&3 holds src kc=slot^((col>>1)&3)
    const int bcol = tid >> 2, bslot = tid & 3;
    const unsigned short* bsrc = Bt + (size_t)(gn0 + bcol) * KDIM +
                                 ((bslot ^ ((bcol >> 1) & 3)) << 3);
    auto stageB = [&](int kt, int buf) {
        gload16(bsrc + kt * 32, &B_lds[buf][tid * 8]);
    };

    f32x4 acc[4][4] = {};
    const int swk = ((lk ^ ((lr >> 1) & 3)) << 3);
    const int arw = lr & 7;                 // row&7 for frag rows (wm*64,m*16 = 0 mod 8)
    const int as0 = (lk * 2) ^ arw;
    const int as1 = (lk * 2 + 1) ^ arw;

    stageA(0, 0);
    stageB(0, 0);
    __syncthreads();

#pragma unroll 1
    for (int kt = 0; kt < 16; ++kt) {
        const int buf = kt & 1;
        if (kt < 15) {
            stageA(kt + 1, buf ^ 1);
            stageB(kt + 1, buf ^ 1);
        }
        bf16x8 af[4], bfr[4];
        uint4 pk[4];
#pragma unroll
        for (int n = 0; n < 4; ++n)
            bfr[n] = *(const bf16x8*)&B_lds[buf][(wn * 64 + n * 16 + lr) * 32 + swk];
#pragma unroll
        for (int m = 0; m < 4; ++m) {
            const int rbase = (wm * 64 + m * 16 + lr) * 32;
            // slot as0 holds source granule lk*2 (k = kt*32 + lk*8 + 0..3),
            // slot as1 holds source granule lk*2+1 (k = kt*32 + lk*8 + 4..7)
            float4 fa = *(const float4*)&A_f[buf][rbase + as0 * 4];
            float4 fb = *(const float4*)&A_f[buf][rbase + as1 * 4];
            uint4 p;
            p.x = pk2(fa.x, fa.y); p.y = pk2(fa.z, fa.w);
            p.z = pk2(fb.x, fb.y); p.w = pk2(fb.z, fb.w);
            pk[m] = p;
            union { uint4 u; bf16x8 v; } cc; cc.u = p;
            af[m] = cc.v;
        }
        if (wrbf) {
            // owner-write bf16 A copy at LINEAR source k-offsets:
            // k-chunk lk of this kt -> unsigned offset kt*16 + lk*4 (+2 for hi)
#pragma unroll
            for (int m = 0; m < 4; ++m) {
                size_t rg = (size_t)(gm0 + wm * 64 + m * 16 + lr);
                unsigned* dst = (unsigned*)(attbf + rg * KDIM) + kt * 16 + lk * 4;
                uint2 lo; lo.x = pk[m].x; lo.y = pk[m].y;
                uint2 hi; hi.x = pk[m].z; hi.y = pk[m].w;
                *(uint2*)(dst)     = lo;
                *(uint2*)(dst + 2) = hi;
            }
        }
#pragma unroll
        for (int m = 0; m < 4; ++m)
#pragma unroll
            for (int n = 0; n < 4; ++n)
                acc[m][n] = __builtin_amdgcn_mfma_f32_16x16x32_bf16(af[m], bfr[n], acc[m][n], 0, 0, 0);
        __syncthreads();
    }

    // ---- epilogue (A_f/B_lds dead; aliased buffers live now) ----
    const int bb0 = gm0 / ATT;
    {
        int j = tid >> 7;                   // 0..3
        int c = tid & 127;
        if (j < 3) {
            int bb = bb0 + j; if (bb > NB - 1) bb = NB - 1;
            ch_s[j * 128 + c] = b_ctx[gn0 + c] + h_emb[(size_t)bb * NDIM + gn0 + c];
        }
        if (tid < 128) wa_s[tid] = Walpha[gn0 + tid];
    }
    __syncthreads();

#pragma unroll
    for (int m = 0; m < 4; ++m) {
#pragma unroll
        for (int r = 0; r < 4; ++r) {
            int rloc = wm * 64 + m * 16 + lk * 4 + r;     // 0..255
            int rg = gm0 + rloc;
            int sel = rg / ATT - bb0;                     // 0..2
            float sum = 0.f;
#pragma unroll
            for (int n = 0; n < 4; ++n) {
                int cloc = wn * 64 + n * 16 + lr;
                sum += fast_tanh(acc[m][n][r] + ch_s[sel * 128 + cloc]) * wa_s[cloc];
            }
            sum += __shfl_xor(sum, 1);
            sum += __shfl_xor(sum, 2);
            sum += __shfl_xor(sum, 4);
            sum += __shfl_xor(sum, 8);
            if (lr == 0) s_red[wn * 256 + rloc] = sum;
        }
    }
    __syncthreads();
    if (tid < 256) {
        float tot = s_red[tid] + s_red[256 + tid];
        int rg = gm0 + tid;
        int bb = rg / ATT;
        atomicAdd(&score[(size_t)bb * 197 + (rg - bb * ATT) + 1], tot);
    }
}

// ---------------------------------------------------------------------------
// Per-batch: sentinel score (pos 0) from sent_emb+h_emb, softmax over 197,
// atten_out[b,:] = al0*sent_lin + sum_s al[s+1]*att[b,s,:] + h_lin
// BF=1: context reads the bf16 att copy (half the bytes).
// ---------------------------------------------------------------------------
template<int BF>
__global__ __launch_bounds__(256) void softmax_chat(
        const float* __restrict__ score, const float* __restrict__ sent_emb,
        const float* __restrict__ h_emb, const float* __restrict__ Walpha,
        const float* __restrict__ sent_lin, const float* __restrict__ h_lin,
        const float* __restrict__ att, const unsigned short* __restrict__ attbf,
        float* __restrict__ atten_out) {
    int b = blockIdx.x, tid = threadIdx.x;
    __shared__ float al[200];
    __shared__ float r4[4];

    float2 se = ((const float2*)(sent_emb + (size_t)b * NDIM))[tid];
    float2 he = ((const float2*)(h_emb + (size_t)b * NDIM))[tid];
    float2 wa = ((const float2*)Walpha)[tid];
    float val = fast_tanh(se.x + he.x) * wa.x + fast_tanh(se.y + he.y) * wa.y;
#pragma unroll
    for (int o = 32; o; o >>= 1) val += __shfl_xor(val, o);
    if ((tid & 63) == 0) r4[tid >> 6] = val;
    __syncthreads();
    float ssent = r4[0] + r4[1] + r4[2] + r4[3];
    __syncthreads();

    float v = -1e30f;
    if (tid < 197) v = (tid == 0) ? ssent : score[(size_t)b * 197 + tid];
    float m = v;
#pragma unroll
    for (int o = 32; o; o >>= 1) m = fmaxf(m, __shfl_xor(m, o));
    if ((tid & 63) == 0) r4[tid >> 6] = m;
    __syncthreads();
    m = fmaxf(fmaxf(r4[0], r4[1]), fmaxf(r4[2], r4[3]));
    __syncthreads();
    float e = (tid < 197) ? __expf(v - m) : 0.f;
    float s = e;
#pragma unroll
    for (int o = 32; o; o >>= 1) s += __shfl_xor(s, o);
    if ((tid & 63) == 0) r4[tid >> 6] = s;
    __syncthreads();
    s = r4[0] + r4[1] + r4[2] + r4[3];
    if (tid < 197) al[tid] = e / s;
    __syncthreads();

    float2 a0 = ((const float2*)(sent_lin + (size_t)b * KDIM))[tid];
    float w0 = al[0];
    float2 accv; accv.x = w0 * a0.x; accv.y = w0 * a0.y;
    if (BF) {
        const unsigned* af = (const unsigned*)attbf + (size_t)b * ATT * 256 + tid;
#pragma unroll 14
        for (int ss = 0; ss < ATT; ++ss) {
            float w = al[ss + 1];
            unsigned uu = af[(size_t)ss * 256];
            union { unsigned u; float f; } lo, hi;
            lo.u = uu << 16; hi.u = uu & 0xffff0000u;
            accv.x += w * lo.f; accv.y += w * hi.f;
        }
    } else {
        const float2* af = (const float2*)(att + (size_t)b * ATT * KDIM);
#pragma unroll 14
        for (int ss = 0; ss < ATT; ++ss) {
            float w = al[ss + 1];
            float2 x = af[(size_t)ss * 256 + tid];
            accv.x += w * x.x; accv.y += w * x.y;
        }
    }
    float2 hl = ((const float2*)(h_lin + (size_t)b * KDIM))[tid];
    accv.x += hl.x; accv.y += hl.y;
    ((float2*)(atten_out + (size_t)b * KDIM))[tid] = accv;
}

// ---------------------------------------------------------------------------
extern "C" void kernel_launch(void* const* d_in, const int* in_sizes, int n_in,
                              void* d_out, int out_size, void* d_ws, size_t ws_size,
                              hipStream_t stream) {
    const float* h     = (const float*)d_in[0];
    const float* sent  = (const float*)d_in[1];
    const float* att   = (const float*)d_in[2];
    const float* W_ctx = (const float*)d_in[3];
    const float* b_ctx = (const float*)d_in[4];
    const float* W_sl  = (const float*)d_in[5];
    const float* b_sl  = (const float*)d_in[6];
    const float* W_se  = (const float*)d_in[7];
    const float* b_se  = (const float*)d_in[8];
    const float* W_hl  = (const float*)d_in[9];
    const float* b_hl  = (const float*)d_in[10];
    const float* W_he  = (const float*)d_in[11];
    const float* b_he  = (const float*)d_in[12];
    const float* W_al  = (const float*)d_in[13];
    // d_in[14] = b_alpha: constant across positions, cancels in softmax
    const float* W_a2h = (const float*)d_in[15];
    const float* b_a2h = (const float*)d_in[16];
    float* out = (float*)d_out;

    char* ws = (char*)d_ws;
    unsigned short* Wt = (unsigned short*)ws;                 // 6 * 512KB bf16 = 3MB
    float* sent_lin = (float*)(ws + 6u * 512 * 1024);
    float* h_lin    = sent_lin + (size_t)NB * 512;
    float* h_emb    = h_lin    + (size_t)NB * 512;
    float* sent_emb = h_emb    + (size_t)NB * 512;
    float* scorebuf = sent_emb + (size_t)NB * 512;            // 1024*197
    float* atten    = scorebuf + (size_t)NB * 197;
    // bf16 att copy (206 MB) — only if workspace is big enough
    char* endp = (char*)(atten + (size_t)NB * 512);
    size_t used = (size_t)(endp - ws);
    used = (used + 255) & ~(size_t)255;
    size_t attbf_bytes = (size_t)NB * ATT * KDIM * sizeof(unsigned short);
    unsigned short* attbf = nullptr;
    if (ws_size >= used + attbf_bytes)
        attbf = (unsigned short*)(ws + used);

    const size_t WSZ = 512 * 512;  // ushorts per weight
    // Wt order: 0=W_sl 1=W_hl 2=W_he 3=W_ctx 4=W_a2h 5=W_se
    prep_weights<<<384, 256, 0, stream>>>(W_sl, W_hl, W_he, W_ctx, W_a2h, W_se, Wt);
    hipMemsetAsync(scorebuf, 0, (size_t)NB * 197 * sizeof(float), stream);

    // sent_lin = relu(sent@W_sl+b_sl); h_lin = tanh(h@W_hl+b_hl)
    gemm64<<<dim3(64, 2), 256, 0, stream>>>(
        sent, Wt + 0 * WSZ, b_sl, sent_lin, 0,
        h,    Wt + 1 * WSZ, b_hl, h_lin,    1);
    // h_emb = h_lin@W_he+b_he; sent_emb = sent_lin@W_se+b_se
    gemm64<<<dim3(64, 2), 256, 0, stream>>>(
        h_lin,    Wt + 2 * WSZ, b_he, h_emb,    2,
        sent_lin, Wt + 5 * WSZ, b_se, sent_emb, 2);

    // visual scores -> scorebuf[b*197 + 1 + s] (+ bf16 att copy from nblk==0)
    gemm_score<<<3136, 512, 0, stream>>>(att, Wt + 3 * WSZ, b_ctx, h_emb, W_al,
                                         scorebuf, attbf);

    if (attbf)
        softmax_chat<1><<<NB, 256, 0, stream>>>(scorebuf, sent_emb, h_emb, W_al,
                                                sent_lin, h_lin, att, attbf, atten);
    else
        softmax_chat<0><<<NB, 256, 0, stream>>>(scorebuf, sent_emb, h_emb, W_al,
                                                sent_lin, h_lin, att, attbf, atten);

    // out = tanh(atten@W_a2h + b_a2h)
    gemm64<<<dim3(64, 1), 256, 0, stream>>>(
        atten, Wt + 4 * WSZ, b_a2h, out, 1,
        atten, Wt + 4 * WSZ, b_a2h, out, 1);
}

// Round 13
// 362.146 us; speedup vs baseline: 1.2619x; 1.0530x over previous
//
#include <hip/hip_runtime.h>
#include <hip/hip_bf16.h>

#define KDIM 512
#define NDIM 512
#define ATT  196
#define NB   1024

typedef __attribute__((ext_vector_type(8))) short bf16x8;
typedef __attribute__((ext_vector_type(8))) unsigned short ushort8;
typedef __attribute__((ext_vector_type(4))) float f32x4;

typedef const __attribute__((address_space(1))) unsigned int gas_uint;
typedef __attribute__((address_space(3))) unsigned int las_uint;

__device__ __forceinline__ void gload16(const void* g, void* l) {
    __builtin_amdgcn_global_load_lds((gas_uint*)g, (las_uint*)l, 16, 0, 0);
}

__device__ __forceinline__ float fast_tanh(float x) {
    x = fminf(15.f, fmaxf(-15.f, x));
    float t = __expf(2.f * x);
    return (t - 1.f) / (t + 1.f);
}

__device__ __forceinline__ unsigned short f2bf(float x) {
    union { float f; unsigned u; } v; v.f = x;
    unsigned r = v.u + 0x7FFF + ((v.u >> 16) & 1);   // RNE
    return (unsigned short)(r >> 16);
}

// single-instruction packed f32x2 -> bf16x2 (RNE). No builtin on gfx950; the
// hip_bf16 header path may expand to a multi-instr SW sequence (T12 recipe).
__device__ __forceinline__ unsigned pk2(float a, float b) {
    unsigned r;
    asm("v_cvt_pk_bf16_f32 %0, %1, %2" : "=v"(r) : "v"(a), "v"(b));
    return r;
}

// ---------------------------------------------------------------------------
// Transpose+cast 6 weights: W[k][n] f32 -> Wt[n][k] bf16 ([n][k] row-major).
// ---------------------------------------------------------------------------
__global__ __launch_bounds__(256) void prep_weights(
        const float* __restrict__ W0, const float* __restrict__ W1,
        const float* __restrict__ W2, const float* __restrict__ W3,
        const float* __restrict__ W4, const float* __restrict__ W5,
        unsigned short* __restrict__ Wt) {
    int w = blockIdx.x >> 6;
    int t = blockIdx.x & 63;
    int k0 = (t >> 3) << 6, n0 = (t & 7) << 6;
    const float* W = (w == 0) ? W0 : (w == 1) ? W1 : (w == 2) ? W2 :
                     (w == 3) ? W3 : (w == 4) ? W4 : W5;
    __shared__ float tile[64][65];
    int tid = threadIdx.x;
    int nc = tid & 15, kr = tid >> 4;
#pragma unroll
    for (int i = 0; i < 4; ++i) {
        int k = kr + i * 16;
        float4 v = *(const float4*)&W[(size_t)(k0 + k) * NDIM + n0 + nc * 4];
        tile[k][nc * 4 + 0] = v.x; tile[k][nc * 4 + 1] = v.y;
        tile[k][nc * 4 + 2] = v.z; tile[k][nc * 4 + 3] = v.w;
    }
    __syncthreads();
    int n = tid >> 2, ks = tid & 3;
    ushort8 v0, v1;
#pragma unroll
    for (int j = 0; j < 8; ++j) v0[j] = f2bf(tile[ks * 16 + j][n]);
#pragma unroll
    for (int j = 0; j < 8; ++j) v1[j] = f2bf(tile[ks * 16 + 8 + j][n]);
    size_t base = ((size_t)w << 18) + (size_t)(n0 + n) * KDIM + k0 + ks * 16;
    *(ushort8*)&Wt[base] = v0;
    *(ushort8*)&Wt[base + 8] = v1;
}

// ---------------------------------------------------------------------------
// Small GEMM: out = act(A[1024,512] @ Wt^T + bias). BM=64, BN=128,
// 256 thr = 4 waves (2Mx2N), wave 32x64. Two ops batched via blockIdx.y.
// act: 0=relu 1=tanh 2=none
// ---------------------------------------------------------------------------
__global__ __launch_bounds__(256) void gemm64(
        const float* __restrict__ A0, const unsigned short* __restrict__ W0,
        const float* __restrict__ bia0, float* __restrict__ O0, int act0,
        const float* __restrict__ A1, const unsigned short* __restrict__ W1,
        const float* __restrict__ bia1, float* __restrict__ O1, int act1) {
    const int op = blockIdx.y;
    const float* A = op ? A1 : A0;
    const unsigned short* Bt = op ? W1 : W0;
    const float* bias = op ? bia1 : bia0;
    float* out = op ? O1 : O0;
    const int act = op ? act1 : act0;

    __shared__ unsigned short A_lds[2][64 * 32];
    __shared__ unsigned short B_lds[2][128 * 32];

    const int tid = threadIdx.x;
    const int gm0 = (blockIdx.x >> 2) * 64, gn0 = (blockIdx.x & 3) * 128;
    const int wid = tid >> 6, lane = tid & 63;
    const int wm = wid >> 1, wn = wid & 1;
    const int lr = lane & 15, lk = lane >> 4;

    const int arow = tid >> 2, akc = tid & 3;
    const float* aptr = A + (size_t)(gm0 + arow) * KDIM + akc * 8;
    const int aoff = arow * 32 + ((akc ^ ((arow >> 1) & 3)) << 3);

    auto stageB = [&](int kt, int buf) {
#pragma unroll
        for (int j = 0; j < 2; ++j) {
            int c = tid + j * 256;
            int col = c >> 2, slot = c & 3;
            const unsigned short* src = Bt + (size_t)(gn0 + col) * KDIM +
                                        ((slot ^ ((col >> 1) & 3)) << 3) + kt * 32;
            gload16(src, &B_lds[buf][c * 8]);
        }
    };

    f32x4 acc[2][4] = {};

    {
        float4 x0 = *(const float4*)aptr;
        float4 x1 = *(const float4*)(aptr + 4);
        stageB(0, 0);
        uint4 p;
        p.x = pk2(x0.x, x0.y); p.y = pk2(x0.z, x0.w);
        p.z = pk2(x1.x, x1.y); p.w = pk2(x1.z, x1.w);
        *(uint4*)&A_lds[0][aoff] = p;
    }
    __syncthreads();

    const int swk = ((lk ^ ((lr >> 1) & 3)) << 3);
    for (int kt = 0; kt < 16; ++kt) {
        const int buf = kt & 1;
        float4 x0, x1;
        if (kt < 15) {
            const float* ap = aptr + (kt + 1) * 32;
            x0 = *(const float4*)ap;
            x1 = *(const float4*)(ap + 4);
            stageB(kt + 1, buf ^ 1);
        }
        bf16x8 af[2], bfr[4];
#pragma unroll
        for (int m = 0; m < 2; ++m)
            af[m] = *(const bf16x8*)&A_lds[buf][(wm * 32 + m * 16 + lr) * 32 + swk];
#pragma unroll
        for (int n = 0; n < 4; ++n)
            bfr[n] = *(const bf16x8*)&B_lds[buf][(wn * 64 + n * 16 + lr) * 32 + swk];
#pragma unroll
        for (int m = 0; m < 2; ++m)
#pragma unroll
            for (int n = 0; n < 4; ++n)
                acc[m][n] = __builtin_amdgcn_mfma_f32_16x16x32_bf16(af[m], bfr[n], acc[m][n], 0, 0, 0);
        if (kt < 15) {
            uint4 p;
            p.x = pk2(x0.x, x0.y); p.y = pk2(x0.z, x0.w);
            p.z = pk2(x1.x, x1.y); p.w = pk2(x1.z, x1.w);
            *(uint4*)&A_lds[buf ^ 1][aoff] = p;
        }
        __syncthreads();
    }

#pragma unroll
    for (int m = 0; m < 2; ++m)
#pragma unroll
        for (int n = 0; n < 4; ++n) {
            int col = gn0 + wn * 64 + n * 16 + lr;
            float bsv = bias[col];
#pragma unroll
            for (int r = 0; r < 4; ++r) {
                int row = gm0 + wm * 32 + m * 16 + lk * 4 + r;
                float v = acc[m][n][r] + bsv;
                if (act == 0) v = fmaxf(v, 0.f);
                else if (act == 1) v = fast_tanh(v);
                out[(size_t)row * NDIM + col] = v;
            }
        }
}

// ---------------------------------------------------------------------------
// Score GEMM (R9 structure, best measured 298us): BM=256, BN=128, 512 thr
// (8 waves, 4Mx2N, wave 64x64). A staged f32 via global_load_lds
// (source-swizzled granules g^=(row&7)), consumer-side cvt (single-instr
// v_cvt_pk_bf16_f32); B via global_load_lds with source-baked swizzle.
// LDS exactly 80 KB -> 2 blocks/CU.
// Epilogue handles up to 3 batch spans; atomicAdd partials into score.
// Grid 3136 = 8 XCD x 98 mtiles x 4 nblk.
// ---------------------------------------------------------------------------
__launch_bounds__(512, 4)
__global__ void gemm_score(const float* __restrict__ A,
                           const unsigned short* __restrict__ Bt,
                           const float* __restrict__ b_ctx,
                           const float* __restrict__ h_emb,
                           const float* __restrict__ Walpha,
                           float* __restrict__ score) {
    __shared__ char smem[81920];
    float (*A_f)[256 * 32] = (float (*)[256 * 32])smem;                       // 2x32KB
    unsigned short (*B_lds)[128 * 32] = (unsigned short (*)[128 * 32])(smem + 65536); // 2x8KB
    // epilogue aliases (A_f region is dead after the K-loop's final barrier)
    float* ch_s = (float*)smem;            // [3][128]
    float* wa_s = (float*)(smem + 1536);   // [128]
    float* s_red = (float*)(smem + 2048);  // [2][256]

    const int tid  = threadIdx.x;
    const int bidx = blockIdx.x;
    const int xcd  = bidx & 7, u = bidx >> 3;
    const int mblk = xcd * 98 + (u >> 2), nblk = u & 3;
    const int gm0  = mblk * 256, gn0 = nblk * 128;

    const int wid = tid >> 6, lane = tid & 63;
    const int wm  = wid >> 1, wn = wid & 1;
    const int lr  = lane & 15, lk = lane >> 4;

    // A staging: granule c (16B f32) -> row=c>>3, dest slot g=c&7 holds
    // source granule g^(row&7). 4 gload_lds/thread, LDS dest linear.
    const float* asrc[4];
#pragma unroll
    for (int i = 0; i < 4; ++i) {
        int c = tid + i * 512;
        int row = c >> 3, g = c & 7;
        asrc[i] = A + (size_t)(gm0 + row) * KDIM + ((g ^ (row & 7)) << 2);
    }
    auto stageA = [&](int kt, int buf) {
#pragma unroll
        for (int i = 0; i < 4; ++i)
            gload16(asrc[i] + kt * 32, &A_f[buf][(tid + i * 512) * 4]);
    };

    // B staging: chunk c=tid -> col=c>>2, slot=c&3 holds src kc=slot^((col>>1)&3)
    const int bcol = tid >> 2, bslot = tid & 3;
    const unsigned short* bsrc = Bt + (size_t)(gn0 + bcol) * KDIM +
                                 ((bslot ^ ((bcol >> 1) & 3)) << 3);
    auto stageB = [&](int kt, int buf) {
        gload16(bsrc + kt * 32, &B_lds[buf][tid * 8]);
    };

    f32x4 acc[4][4] = {};
    const int swk = ((lk ^ ((lr >> 1) & 3)) << 3);
    const int arw = lr & 7;                 // row&7 for frag rows (wm*64,m*16 = 0 mod 8)
    const int as0 = (lk * 2) ^ arw;
    const int as1 = (lk * 2 + 1) ^ arw;

    stageA(0, 0);
    stageB(0, 0);
    __syncthreads();

#pragma unroll 1
    for (int kt = 0; kt < 16; ++kt) {
        const int buf = kt & 1;
        if (kt < 15) {
            stageA(kt + 1, buf ^ 1);
            stageB(kt + 1, buf ^ 1);
        }
        bf16x8 af[4], bfr[4];
#pragma unroll
        for (int n = 0; n < 4; ++n)
            bfr[n] = *(const bf16x8*)&B_lds[buf][(wn * 64 + n * 16 + lr) * 32 + swk];
#pragma unroll
        for (int m = 0; m < 4; ++m) {
            const int rbase = (wm * 64 + m * 16 + lr) * 32;
            float4 fa = *(const float4*)&A_f[buf][rbase + as0 * 4];
            float4 fb = *(const float4*)&A_f[buf][rbase + as1 * 4];
            uint4 p;
            p.x = pk2(fa.x, fa.y); p.y = pk2(fa.z, fa.w);
            p.z = pk2(fb.x, fb.y); p.w = pk2(fb.z, fb.w);
            union { uint4 u; bf16x8 v; } cc; cc.u = p;
            af[m] = cc.v;
        }
#pragma unroll
        for (int m = 0; m < 4; ++m)
#pragma unroll
            for (int n = 0; n < 4; ++n)
                acc[m][n] = __builtin_amdgcn_mfma_f32_16x16x32_bf16(af[m], bfr[n], acc[m][n], 0, 0, 0);
        __syncthreads();
    }

    // ---- epilogue (A_f/B_lds dead; aliased buffers live now) ----
    const int bb0 = gm0 / ATT;
    {
        int j = tid >> 7;                   // 0..3
        int c = tid & 127;
        if (j < 3) {
            int bb = bb0 + j; if (bb > NB - 1) bb = NB - 1;
            ch_s[j * 128 + c] = b_ctx[gn0 + c] + h_emb[(size_t)bb * NDIM + gn0 + c];
        }
        if (tid < 128) wa_s[tid] = Walpha[gn0 + tid];
    }
    __syncthreads();

#pragma unroll
    for (int m = 0; m < 4; ++m) {
#pragma unroll
        for (int r = 0; r < 4; ++r) {
            int rloc = wm * 64 + m * 16 + lk * 4 + r;     // 0..255
            int rg = gm0 + rloc;
            int sel = rg / ATT - bb0;                     // 0..2
            float sum = 0.f;
#pragma unroll
            for (int n = 0; n < 4; ++n) {
                int cloc = wn * 64 + n * 16 + lr;
                sum += fast_tanh(acc[m][n][r] + ch_s[sel * 128 + cloc]) * wa_s[cloc];
            }
            sum += __shfl_xor(sum, 1);
            sum += __shfl_xor(sum, 2);
            sum += __shfl_xor(sum, 4);
            sum += __shfl_xor(sum, 8);
            if (lr == 0) s_red[wn * 256 + rloc] = sum;
        }
    }
    __syncthreads();
    if (tid < 256) {
        float tot = s_red[tid] + s_red[256 + tid];
        int rg = gm0 + tid;
        int bb = rg / ATT;
        atomicAdd(&score[(size_t)bb * 197 + (rg - bb * ATT) + 1], tot);
    }
}

// ---------------------------------------------------------------------------
// Per-batch: sentinel score (pos 0) from sent_emb+h_emb, softmax over 197,
// atten_out[b,:] = al0*sent_lin + sum_s al[s+1]*att[b,s,:] + h_lin
// ---------------------------------------------------------------------------
__global__ __launch_bounds__(256) void softmax_chat(
        const float* __restrict__ score, const float* __restrict__ sent_emb,
        const float* __restrict__ h_emb, const float* __restrict__ Walpha,
        const float* __restrict__ sent_lin, const float* __restrict__ h_lin,
        const float* __restrict__ att, float* __restrict__ atten_out) {
    int b = blockIdx.x, tid = threadIdx.x;
    __shared__ float al[200];
    __shared__ float r4[4];

    float2 se = ((const float2*)(sent_emb + (size_t)b * NDIM))[tid];
    float2 he = ((const float2*)(h_emb + (size_t)b * NDIM))[tid];
    float2 wa = ((const float2*)Walpha)[tid];
    float val = fast_tanh(se.x + he.x) * wa.x + fast_tanh(se.y + he.y) * wa.y;
#pragma unroll
    for (int o = 32; o; o >>= 1) val += __shfl_xor(val, o);
    if ((tid & 63) == 0) r4[tid >> 6] = val;
    __syncthreads();
    float ssent = r4[0] + r4[1] + r4[2] + r4[3];
    __syncthreads();

    float v = -1e30f;
    if (tid < 197) v = (tid == 0) ? ssent : score[(size_t)b * 197 + tid];
    float m = v;
#pragma unroll
    for (int o = 32; o; o >>= 1) m = fmaxf(m, __shfl_xor(m, o));
    if ((tid & 63) == 0) r4[tid >> 6] = m;
    __syncthreads();
    m = fmaxf(fmaxf(r4[0], r4[1]), fmaxf(r4[2], r4[3]));
    __syncthreads();
    float e = (tid < 197) ? __expf(v - m) : 0.f;
    float s = e;
#pragma unroll
    for (int o = 32; o; o >>= 1) s += __shfl_xor(s, o);
    if ((tid & 63) == 0) r4[tid >> 6] = s;
    __syncthreads();
    s = r4[0] + r4[1] + r4[2] + r4[3];
    if (tid < 197) al[tid] = e / s;
    __syncthreads();

    const float2* af = (const float2*)(att + (size_t)b * ATT * KDIM);
    float2 a0 = ((const float2*)(sent_lin + (size_t)b * KDIM))[tid];
    float w0 = al[0];
    float2 accv; accv.x = w0 * a0.x; accv.y = w0 * a0.y;
#pragma unroll 14
    for (int ss = 0; ss < ATT; ++ss) {
        float w = al[ss + 1];
        float2 x = af[(size_t)ss * 256 + tid];
        accv.x += w * x.x; accv.y += w * x.y;
    }
    float2 hl = ((const float2*)(h_lin + (size_t)b * KDIM))[tid];
    accv.x += hl.x; accv.y += hl.y;
    ((float2*)(atten_out + (size_t)b * KDIM))[tid] = accv;
}

// ---------------------------------------------------------------------------
extern "C" void kernel_launch(void* const* d_in, const int* in_sizes, int n_in,
                              void* d_out, int out_size, void* d_ws, size_t ws_size,
                              hipStream_t stream) {
    const float* h     = (const float*)d_in[0];
    const float* sent  = (const float*)d_in[1];
    const float* att   = (const float*)d_in[2];
    const float* W_ctx = (const float*)d_in[3];
    const float* b_ctx = (const float*)d_in[4];
    const float* W_sl  = (const float*)d_in[5];
    const float* b_sl  = (const float*)d_in[6];
    const float* W_se  = (const float*)d_in[7];
    const float* b_se  = (const float*)d_in[8];
    const float* W_hl  = (const float*)d_in[9];
    const float* b_hl  = (const float*)d_in[10];
    const float* W_he  = (const float*)d_in[11];
    const float* b_he  = (const float*)d_in[12];
    const float* W_al  = (const float*)d_in[13];
    // d_in[14] = b_alpha: constant across positions, cancels in softmax
    const float* W_a2h = (const float*)d_in[15];
    const float* b_a2h = (const float*)d_in[16];
    float* out = (float*)d_out;

    char* ws = (char*)d_ws;
    unsigned short* Wt = (unsigned short*)ws;                 // 6 * 512KB bf16 = 3MB
    float* sent_lin = (float*)(ws + 6u * 512 * 1024);
    float* h_lin    = sent_lin + (size_t)NB * 512;
    float* h_emb    = h_lin    + (size_t)NB * 512;
    float* sent_emb = h_emb    + (size_t)NB * 512;
    float* scorebuf = sent_emb + (size_t)NB * 512;            // 1024*197
    float* atten    = scorebuf + (size_t)NB * 197;

    const size_t WSZ = 512 * 512;  // ushorts per weight
    // Wt order: 0=W_sl 1=W_hl 2=W_he 3=W_ctx 4=W_a2h 5=W_se
    prep_weights<<<384, 256, 0, stream>>>(W_sl, W_hl, W_he, W_ctx, W_a2h, W_se, Wt);
    hipMemsetAsync(scorebuf, 0, (size_t)NB * 197 * sizeof(float), stream);

    // sent_lin = relu(sent@W_sl+b_sl); h_lin = tanh(h@W_hl+b_hl)
    gemm64<<<dim3(64, 2), 256, 0, stream>>>(
        sent, Wt + 0 * WSZ, b_sl, sent_lin, 0,
        h,    Wt + 1 * WSZ, b_hl, h_lin,    1);
    // h_emb = h_lin@W_he+b_he; sent_emb = sent_lin@W_se+b_se
    gemm64<<<dim3(64, 2), 256, 0, stream>>>(
        h_lin,    Wt + 2 * WSZ, b_he, h_emb,    2,
        sent_lin, Wt + 5 * WSZ, b_se, sent_emb, 2);

    // visual scores -> scorebuf[b*197 + 1 + s]
    gemm_score<<<3136, 512, 0, stream>>>(att, Wt + 3 * WSZ, b_ctx, h_emb, W_al, scorebuf);

    softmax_chat<<<NB, 256, 0, stream>>>(scorebuf, sent_emb, h_emb, W_al,
                                         sent_lin, h_lin, att, atten);

    // out = tanh(atten@W_a2h + b_a2h)
    gemm64<<<dim3(64, 1), 256, 0, stream>>>(
        atten, Wt + 4 * WSZ, b_a2h, out, 1,
        atten, Wt + 4 * WSZ, b_a2h, out, 1);
}

// Round 14
// 361.262 us; speedup vs baseline: 1.2650x; 1.0024x over previous
//
#include <hip/hip_runtime.h>
#include <hip/hip_bf16.h>

#define KDIM 512
#define NDIM 512
#define ATT  196
#define NB   1024

typedef __attribute__((ext_vector_type(8))) short bf16x8;
typedef __attribute__((ext_vector_type(8))) unsigned short ushort8;
typedef __attribute__((ext_vector_type(4))) float f32x4;

typedef const __attribute__((address_space(1))) unsigned int gas_uint;
typedef __attribute__((address_space(3))) unsigned int las_uint;

__device__ __forceinline__ void gload16(const void* g, void* l) {
    __builtin_amdgcn_global_load_lds((gas_uint*)g, (las_uint*)l, 16, 0, 0);
}

__device__ __forceinline__ float fast_tanh(float x) {
    x = fminf(15.f, fmaxf(-15.f, x));
    float t = __expf(2.f * x);
    return (t - 1.f) / (t + 1.f);
}

__device__ __forceinline__ unsigned short f2bf(float x) {
    union { float f; unsigned u; } v; v.f = x;
    unsigned r = v.u + 0x7FFF + ((v.u >> 16) & 1);   // RNE
    return (unsigned short)(r >> 16);
}

// single-instruction packed f32x2 -> bf16x2 (RNE)
__device__ __forceinline__ unsigned pk2(float a, float b) {
    unsigned r;
    asm("v_cvt_pk_bf16_f32 %0, %1, %2" : "=v"(r) : "v"(a), "v"(b));
    return r;
}

// ---------------------------------------------------------------------------
// Transpose+cast 6 weights: W[k][n] f32 -> Wt[n][k] bf16 ([n][k] row-major).
// ---------------------------------------------------------------------------
__global__ __launch_bounds__(256) void prep_weights(
        const float* __restrict__ W0, const float* __restrict__ W1,
        const float* __restrict__ W2, const float* __restrict__ W3,
        const float* __restrict__ W4, const float* __restrict__ W5,
        unsigned short* __restrict__ Wt) {
    int w = blockIdx.x >> 6;
    int t = blockIdx.x & 63;
    int k0 = (t >> 3) << 6, n0 = (t & 7) << 6;
    const float* W = (w == 0) ? W0 : (w == 1) ? W1 : (w == 2) ? W2 :
                     (w == 3) ? W3 : (w == 4) ? W4 : W5;
    __shared__ float tile[64][65];
    int tid = threadIdx.x;
    int nc = tid & 15, kr = tid >> 4;
#pragma unroll
    for (int i = 0; i < 4; ++i) {
        int k = kr + i * 16;
        float4 v = *(const float4*)&W[(size_t)(k0 + k) * NDIM + n0 + nc * 4];
        tile[k][nc * 4 + 0] = v.x; tile[k][nc * 4 + 1] = v.y;
        tile[k][nc * 4 + 2] = v.z; tile[k][nc * 4 + 3] = v.w;
    }
    __syncthreads();
    int n = tid >> 2, ks = tid & 3;
    ushort8 v0, v1;
#pragma unroll
    for (int j = 0; j < 8; ++j) v0[j] = f2bf(tile[ks * 16 + j][n]);
#pragma unroll
    for (int j = 0; j < 8; ++j) v1[j] = f2bf(tile[ks * 16 + 8 + j][n]);
    size_t base = ((size_t)w << 18) + (size_t)(n0 + n) * KDIM + k0 + ks * 16;
    *(ushort8*)&Wt[base] = v0;
    *(ushort8*)&Wt[base + 8] = v1;
}

// ---------------------------------------------------------------------------
// Small GEMM: out = act(A[1024,512] @ Wt^T + bias). BM=64, BN=128,
// 256 thr = 4 waves (2Mx2N), wave 32x64. Two ops batched via blockIdx.y.
// act: 0=relu 1=tanh 2=none
// ---------------------------------------------------------------------------
__global__ __launch_bounds__(256) void gemm64(
        const float* __restrict__ A0, const unsigned short* __restrict__ W0,
        const float* __restrict__ bia0, float* __restrict__ O0, int act0,
        const float* __restrict__ A1, const unsigned short* __restrict__ W1,
        const float* __restrict__ bia1, float* __restrict__ O1, int act1) {
    const int op = blockIdx.y;
    const float* A = op ? A1 : A0;
    const unsigned short* Bt = op ? W1 : W0;
    const float* bias = op ? bia1 : bia0;
    float* out = op ? O1 : O0;
    const int act = op ? act1 : act0;

    __shared__ unsigned short A_lds[2][64 * 32];
    __shared__ unsigned short B_lds[2][128 * 32];

    const int tid = threadIdx.x;
    const int gm0 = (blockIdx.x >> 2) * 64, gn0 = (blockIdx.x & 3) * 128;
    const int wid = tid >> 6, lane = tid & 63;
    const int wm = wid >> 1, wn = wid & 1;
    const int lr = lane & 15, lk = lane >> 4;

    const int arow = tid >> 2, akc = tid & 3;
    const float* aptr = A + (size_t)(gm0 + arow) * KDIM + akc * 8;
    const int aoff = arow * 32 + ((akc ^ ((arow >> 1) & 3)) << 3);

    auto stageB = [&](int kt, int buf) {
#pragma unroll
        for (int j = 0; j < 2; ++j) {
            int c = tid + j * 256;
            int col = c >> 2, slot = c & 3;
            const unsigned short* src = Bt + (size_t)(gn0 + col) * KDIM +
                                        ((slot ^ ((col >> 1) & 3)) << 3) + kt * 32;
            gload16(src, &B_lds[buf][c * 8]);
        }
    };

    f32x4 acc[2][4] = {};

    {
        float4 x0 = *(const float4*)aptr;
        float4 x1 = *(const float4*)(aptr + 4);
        stageB(0, 0);
        uint4 p;
        p.x = pk2(x0.x, x0.y); p.y = pk2(x0.z, x0.w);
        p.z = pk2(x1.x, x1.y); p.w = pk2(x1.z, x1.w);
        *(uint4*)&A_lds[0][aoff] = p;
    }
    __syncthreads();

    const int swk = ((lk ^ ((lr >> 1) & 3)) << 3);
    for (int kt = 0; kt < 16; ++kt) {
        const int buf = kt & 1;
        float4 x0, x1;
        if (kt < 15) {
            const float* ap = aptr + (kt + 1) * 32;
            x0 = *(const float4*)ap;
            x1 = *(const float4*)(ap + 4);
            stageB(kt + 1, buf ^ 1);
        }
        bf16x8 af[2], bfr[4];
#pragma unroll
        for (int m = 0; m < 2; ++m)
            af[m] = *(const bf16x8*)&A_lds[buf][(wm * 32 + m * 16 + lr) * 32 + swk];
#pragma unroll
        for (int n = 0; n < 4; ++n)
            bfr[n] = *(const bf16x8*)&B_lds[buf][(wn * 64 + n * 16 + lr) * 32 + swk];
#pragma unroll
        for (int m = 0; m < 2; ++m)
#pragma unroll
            for (int n = 0; n < 4; ++n)
                acc[m][n] = __builtin_amdgcn_mfma_f32_16x16x32_bf16(af[m], bfr[n], acc[m][n], 0, 0, 0);
        if (kt < 15) {
            uint4 p;
            p.x = pk2(x0.x, x0.y); p.y = pk2(x0.z, x0.w);
            p.z = pk2(x1.x, x1.y); p.w = pk2(x1.z, x1.w);
            *(uint4*)&A_lds[buf ^ 1][aoff] = p;
        }
        __syncthreads();
    }

#pragma unroll
    for (int m = 0; m < 2; ++m)
#pragma unroll
        for (int n = 0; n < 4; ++n) {
            int col = gn0 + wn * 64 + n * 16 + lr;
            float bsv = bias[col];
#pragma unroll
            for (int r = 0; r < 4; ++r) {
                int row = gm0 + wm * 32 + m * 16 + lk * 4 + r;
                float v = acc[m][n][r] + bsv;
                if (act == 0) v = fmaxf(v, 0.f);
                else if (act == 1) v = fast_tanh(v);
                out[(size_t)row * NDIM + col] = v;
            }
        }
}

// ---------------------------------------------------------------------------
// Score GEMM, R14: BM=256, BN=128, 512 thr (8 waves, 4Mx2N, wave 64x64).
// A reg-staged to bf16 LDS (T14: 4xfloat4 loads issued at loop top for t+1;
// cvt_pk + 2x ds_write AFTER the MFMA cluster). Consumer reads A as bf16
// directly (no cvt on MFMA chain). B via global_load_lds, source-baked
// swizzle. LDS 48 KB (A 2x16KB bf16 + B 2x8KB) -> 2 blocks/CU.
// LDS traffic/thread/step: 160 B vs 272 B for the f32-A variant.
// Epilogue handles up to 3 batch spans; atomicAdd partials into score.
// Grid 3136 = 8 XCD x 98 mtiles x 4 nblk.
// ---------------------------------------------------------------------------
__launch_bounds__(512, 4)
__global__ void gemm_score(const float* __restrict__ A,
                           const unsigned short* __restrict__ Bt,
                           const float* __restrict__ b_ctx,
                           const float* __restrict__ h_emb,
                           const float* __restrict__ Walpha,
                           float* __restrict__ score) {
    __shared__ char smem[49152];
    unsigned short (*A_lds)[256 * 32] = (unsigned short (*)[256 * 32])smem;          // 2x16KB bf16
    unsigned short (*B_lds)[128 * 32] = (unsigned short (*)[128 * 32])(smem + 32768); // 2x8KB
    // epilogue aliases (A_lds region dead after final barrier)
    float* ch_s = (float*)smem;            // [3][128]
    float* wa_s = (float*)(smem + 1536);   // [128]
    float* s_red = (float*)(smem + 2048);  // [2][256]

    const int tid  = threadIdx.x;
    const int bidx = blockIdx.x;
    const int xcd  = bidx & 7, u = bidx >> 3;
    const int mblk = xcd * 98 + (u >> 2), nblk = u & 3;
    const int gm0  = mblk * 256, gn0 = nblk * 128;

    const int wid = tid >> 6, lane = tid & 63;
    const int wm  = wid >> 1, wn = wid & 1;
    const int lr  = lane & 15, lk = lane >> 4;

    // A staging: thread -> row=tid>>1 (0..255), khalf=tid&1 (16 f32 = granules
    // 2a,2a+1). Granule g lands at slot g^((row>>1)&3) (R4-verified swizzle).
    const int arow = tid >> 1, ahalf = tid & 1;
    const float* aptr = A + (size_t)(gm0 + arow) * KDIM + ahalf * 16;
    const int skc0  = (ahalf * 2) ^ ((arow >> 1) & 3);
    const int aoff0 = arow * 32 + skc0 * 8;
    const int aoff1 = arow * 32 + (skc0 ^ 1) * 8;

    // B staging: chunk c=tid -> col=c>>2, slot=c&3 holds src kc=slot^((col>>1)&3)
    const int bcol = tid >> 2, bslot = tid & 3;
    const unsigned short* bsrc = Bt + (size_t)(gn0 + bcol) * KDIM +
                                 ((bslot ^ ((bcol >> 1) & 3)) << 3);
    auto stageB = [&](int kt, int buf) {
        gload16(bsrc + kt * 32, &B_lds[buf][tid * 8]);
    };
    auto writeA = [&](const float4& x0, const float4& x1,
                      const float4& x2, const float4& x3, int buf) {
        uint4 p0, p1;
        p0.x = pk2(x0.x, x0.y); p0.y = pk2(x0.z, x0.w);
        p0.z = pk2(x1.x, x1.y); p0.w = pk2(x1.z, x1.w);
        p1.x = pk2(x2.x, x2.y); p1.y = pk2(x2.z, x2.w);
        p1.z = pk2(x3.x, x3.y); p1.w = pk2(x3.z, x3.w);
        *(uint4*)&A_lds[buf][aoff0] = p0;
        *(uint4*)&A_lds[buf][aoff1] = p1;
    };

    f32x4 acc[4][4] = {};
    const int swk = ((lk ^ ((lr >> 1) & 3)) << 3);

    // prologue: stage tile 0
    {
        float4 x0 = *(const float4*)(aptr);
        float4 x1 = *(const float4*)(aptr + 4);
        float4 x2 = *(const float4*)(aptr + 8);
        float4 x3 = *(const float4*)(aptr + 12);
        stageB(0, 0);
        writeA(x0, x1, x2, x3, 0);
    }
    __syncthreads();

#pragma unroll 1
    for (int kt = 0; kt < 16; ++kt) {
        const int buf = kt & 1;
        float4 x0, x1, x2, x3;
        if (kt < 15) {
            const float* ap = aptr + (kt + 1) * 32;
            x0 = *(const float4*)(ap);
            x1 = *(const float4*)(ap + 4);
            x2 = *(const float4*)(ap + 8);
            x3 = *(const float4*)(ap + 12);
            stageB(kt + 1, buf ^ 1);
        }
        bf16x8 af[4], bfr[4];
#pragma unroll
        for (int n = 0; n < 4; ++n)
            bfr[n] = *(const bf16x8*)&B_lds[buf][(wn * 64 + n * 16 + lr) * 32 + swk];
#pragma unroll
        for (int m = 0; m < 4; ++m)
            af[m] = *(const bf16x8*)&A_lds[buf][(wm * 64 + m * 16 + lr) * 32 + swk];
#pragma unroll
        for (int m = 0; m < 4; ++m)
#pragma unroll
            for (int n = 0; n < 4; ++n)
                acc[m][n] = __builtin_amdgcn_mfma_f32_16x16x32_bf16(af[m], bfr[n], acc[m][n], 0, 0, 0);
        if (kt < 15) writeA(x0, x1, x2, x3, buf ^ 1);
        __syncthreads();
    }

    // ---- epilogue (A_lds/B_lds dead; aliased buffers live now) ----
    const int bb0 = gm0 / ATT;
    {
        int j = tid >> 7;                   // 0..3
        int c = tid & 127;
        if (j < 3) {
            int bb = bb0 + j; if (bb > NB - 1) bb = NB - 1;
            ch_s[j * 128 + c] = b_ctx[gn0 + c] + h_emb[(size_t)bb * NDIM + gn0 + c];
        }
        if (tid < 128) wa_s[tid] = Walpha[gn0 + tid];
    }
    __syncthreads();

#pragma unroll
    for (int m = 0; m < 4; ++m) {
#pragma unroll
        for (int r = 0; r < 4; ++r) {
            int rloc = wm * 64 + m * 16 + lk * 4 + r;     // 0..255
            int rg = gm0 + rloc;
            int sel = rg / ATT - bb0;                     // 0..2
            float sum = 0.f;
#pragma unroll
            for (int n = 0; n < 4; ++n) {
                int cloc = wn * 64 + n * 16 + lr;
                sum += fast_tanh(acc[m][n][r] + ch_s[sel * 128 + cloc]) * wa_s[cloc];
            }
            sum += __shfl_xor(sum, 1);
            sum += __shfl_xor(sum, 2);
            sum += __shfl_xor(sum, 4);
            sum += __shfl_xor(sum, 8);
            if (lr == 0) s_red[wn * 256 + rloc] = sum;
        }
    }
    __syncthreads();
    if (tid < 256) {
        float tot = s_red[tid] + s_red[256 + tid];
        int rg = gm0 + tid;
        int bb = rg / ATT;
        atomicAdd(&score[(size_t)bb * 197 + (rg - bb * ATT) + 1], tot);
    }
}

// ---------------------------------------------------------------------------
// Per-batch: sentinel score (pos 0) from sent_emb+h_emb, softmax over 197,
// atten_out[b,:] = al0*sent_lin + sum_s al[s+1]*att[b,s,:] + h_lin
// ---------------------------------------------------------------------------
__global__ __launch_bounds__(256) void softmax_chat(
        const float* __restrict__ score, const float* __restrict__ sent_emb,
        const float* __restrict__ h_emb, const float* __restrict__ Walpha,
        const float* __restrict__ sent_lin, const float* __restrict__ h_lin,
        const float* __restrict__ att, float* __restrict__ atten_out) {
    int b = blockIdx.x, tid = threadIdx.x;
    __shared__ float al[200];
    __shared__ float r4[4];

    float2 se = ((const float2*)(sent_emb + (size_t)b * NDIM))[tid];
    float2 he = ((const float2*)(h_emb + (size_t)b * NDIM))[tid];
    float2 wa = ((const float2*)Walpha)[tid];
    float val = fast_tanh(se.x + he.x) * wa.x + fast_tanh(se.y + he.y) * wa.y;
#pragma unroll
    for (int o = 32; o; o >>= 1) val += __shfl_xor(val, o);
    if ((tid & 63) == 0) r4[tid >> 6] = val;
    __syncthreads();
    float ssent = r4[0] + r4[1] + r4[2] + r4[3];
    __syncthreads();

    float v = -1e30f;
    if (tid < 197) v = (tid == 0) ? ssent : score[(size_t)b * 197 + tid];
    float m = v;
#pragma unroll
    for (int o = 32; o; o >>= 1) m = fmaxf(m, __shfl_xor(m, o));
    if ((tid & 63) == 0) r4[tid >> 6] = m;
    __syncthreads();
    m = fmaxf(fmaxf(r4[0], r4[1]), fmaxf(r4[2], r4[3]));
    __syncthreads();
    float e = (tid < 197) ? __expf(v - m) : 0.f;
    float s = e;
#pragma unroll
    for (int o = 32; o; o >>= 1) s += __shfl_xor(s, o);
    if ((tid & 63) == 0) r4[tid >> 6] = s;
    __syncthreads();
    s = r4[0] + r4[1] + r4[2] + r4[3];
    if (tid < 197) al[tid] = e / s;
    __syncthreads();

    const float2* af = (const float2*)(att + (size_t)b * ATT * KDIM);
    float2 a0 = ((const float2*)(sent_lin + (size_t)b * KDIM))[tid];
    float w0 = al[0];
    float2 accv; accv.x = w0 * a0.x; accv.y = w0 * a0.y;
#pragma unroll 14
    for (int ss = 0; ss < ATT; ++ss) {
        float w = al[ss + 1];
        float2 x = af[(size_t)ss * 256 + tid];
        accv.x += w * x.x; accv.y += w * x.y;
    }
    float2 hl = ((const float2*)(h_lin + (size_t)b * KDIM))[tid];
    accv.x += hl.x; accv.y += hl.y;
    ((float2*)(atten_out + (size_t)b * KDIM))[tid] = accv;
}

// ---------------------------------------------------------------------------
extern "C" void kernel_launch(void* const* d_in, const int* in_sizes, int n_in,
                              void* d_out, int out_size, void* d_ws, size_t ws_size,
                              hipStream_t stream) {
    const float* h     = (const float*)d_in[0];
    const float* sent  = (const float*)d_in[1];
    const float* att   = (const float*)d_in[2];
    const float* W_ctx = (const float*)d_in[3];
    const float* b_ctx = (const float*)d_in[4];
    const float* W_sl  = (const float*)d_in[5];
    const float* b_sl  = (const float*)d_in[6];
    const float* W_se  = (const float*)d_in[7];
    const float* b_se  = (const float*)d_in[8];
    const float* W_hl  = (const float*)d_in[9];
    const float* b_hl  = (const float*)d_in[10];
    const float* W_he  = (const float*)d_in[11];
    const float* b_he  = (const float*)d_in[12];
    const float* W_al  = (const float*)d_in[13];
    // d_in[14] = b_alpha: constant across positions, cancels in softmax
    const float* W_a2h = (const float*)d_in[15];
    const float* b_a2h = (const float*)d_in[16];
    float* out = (float*)d_out;

    char* ws = (char*)d_ws;
    unsigned short* Wt = (unsigned short*)ws;                 // 6 * 512KB bf16 = 3MB
    float* sent_lin = (float*)(ws + 6u * 512 * 1024);
    float* h_lin    = sent_lin + (size_t)NB * 512;
    float* h_emb    = h_lin    + (size_t)NB * 512;
    float* sent_emb = h_emb    + (size_t)NB * 512;
    float* scorebuf = sent_emb + (size_t)NB * 512;            // 1024*197
    float* atten    = scorebuf + (size_t)NB * 197;

    const size_t WSZ = 512 * 512;  // ushorts per weight
    // Wt order: 0=W_sl 1=W_hl 2=W_he 3=W_ctx 4=W_a2h 5=W_se
    prep_weights<<<384, 256, 0, stream>>>(W_sl, W_hl, W_he, W_ctx, W_a2h, W_se, Wt);
    hipMemsetAsync(scorebuf, 0, (size_t)NB * 197 * sizeof(float), stream);

    // sent_lin = relu(sent@W_sl+b_sl); h_lin = tanh(h@W_hl+b_hl)
    gemm64<<<dim3(64, 2), 256, 0, stream>>>(
        sent, Wt + 0 * WSZ, b_sl, sent_lin, 0,
        h,    Wt + 1 * WSZ, b_hl, h_lin,    1);
    // h_emb = h_lin@W_he+b_he; sent_emb = sent_lin@W_se+b_se
    gemm64<<<dim3(64, 2), 256, 0, stream>>>(
        h_lin,    Wt + 2 * WSZ, b_he, h_emb,    2,
        sent_lin, Wt + 5 * WSZ, b_se, sent_emb, 2);

    // visual scores -> scorebuf[b*197 + 1 + s]
    gemm_score<<<3136, 512, 0, stream>>>(att, Wt + 3 * WSZ, b_ctx, h_emb, W_al, scorebuf);

    softmax_chat<<<NB, 256, 0, stream>>>(scorebuf, sent_emb, h_emb, W_al,
                                         sent_lin, h_lin, att, atten);

    // out = tanh(atten@W_a2h + b_a2h)
    gemm64<<<dim3(64, 1), 256, 0, stream>>>(
        atten, Wt + 4 * WSZ, b_a2h, out, 1,
        atten, Wt + 4 * WSZ, b_a2h, out, 1);
}

// Round 15
// 359.098 us; speedup vs baseline: 1.2726x; 1.0060x over previous
//
#include <hip/hip_runtime.h>
#include <hip/hip_bf16.h>

#define KDIM 512
#define NDIM 512
#define ATT  196
#define NB   1024

typedef __attribute__((ext_vector_type(8))) short bf16x8;
typedef __attribute__((ext_vector_type(8))) unsigned short ushort8;
typedef __attribute__((ext_vector_type(4))) float f32x4;

typedef const __attribute__((address_space(1))) unsigned int gas_uint;
typedef __attribute__((address_space(3))) unsigned int las_uint;

__device__ __forceinline__ void gload16(const void* g, void* l) {
    __builtin_amdgcn_global_load_lds((gas_uint*)g, (las_uint*)l, 16, 0, 0);
}

__device__ __forceinline__ float fast_tanh(float x) {
    x = fminf(15.f, fmaxf(-15.f, x));
    float t = __expf(2.f * x);
    return (t - 1.f) / (t + 1.f);
}

__device__ __forceinline__ unsigned short f2bf(float x) {
    union { float f; unsigned u; } v; v.f = x;
    unsigned r = v.u + 0x7FFF + ((v.u >> 16) & 1);   // RNE
    return (unsigned short)(r >> 16);
}

// single-instruction packed f32x2 -> bf16x2 (RNE)
__device__ __forceinline__ unsigned pk2(float a, float b) {
    unsigned r;
    asm("v_cvt_pk_bf16_f32 %0, %1, %2" : "=v"(r) : "v"(a), "v"(b));
    return r;
}

// ---------------------------------------------------------------------------
// Transpose+cast 6 weights: W[k][n] f32 -> Wt[n][k] bf16 ([n][k] row-major).
// Also zeroes scorebuf (folded memset; runs before gemm_score on the stream).
// ---------------------------------------------------------------------------
__global__ __launch_bounds__(256) void prep_weights(
        const float* __restrict__ W0, const float* __restrict__ W1,
        const float* __restrict__ W2, const float* __restrict__ W3,
        const float* __restrict__ W4, const float* __restrict__ W5,
        unsigned short* __restrict__ Wt, float* __restrict__ scorebuf) {
    int w = blockIdx.x >> 6;
    int t = blockIdx.x & 63;
    int k0 = (t >> 3) << 6, n0 = (t & 7) << 6;
    const float* W = (w == 0) ? W0 : (w == 1) ? W1 : (w == 2) ? W2 :
                     (w == 3) ? W3 : (w == 4) ? W4 : W5;
    __shared__ float tile[64][65];
    int tid = threadIdx.x;
    // folded scorebuf zeroing (grid-stride over 1024*197)
    for (int i = blockIdx.x * 256 + tid; i < NB * 197; i += gridDim.x * 256)
        scorebuf[i] = 0.f;
    int nc = tid & 15, kr = tid >> 4;
#pragma unroll
    for (int i = 0; i < 4; ++i) {
        int k = kr + i * 16;
        float4 v = *(const float4*)&W[(size_t)(k0 + k) * NDIM + n0 + nc * 4];
        tile[k][nc * 4 + 0] = v.x; tile[k][nc * 4 + 1] = v.y;
        tile[k][nc * 4 + 2] = v.z; tile[k][nc * 4 + 3] = v.w;
    }
    __syncthreads();
    int n = tid >> 2, ks = tid & 3;
    ushort8 v0, v1;
#pragma unroll
    for (int j = 0; j < 8; ++j) v0[j] = f2bf(tile[ks * 16 + j][n]);
#pragma unroll
    for (int j = 0; j < 8; ++j) v1[j] = f2bf(tile[ks * 16 + 8 + j][n]);
    size_t base = ((size_t)w << 18) + (size_t)(n0 + n) * KDIM + k0 + ks * 16;
    *(ushort8*)&Wt[base] = v0;
    *(ushort8*)&Wt[base + 8] = v1;
}

// ---------------------------------------------------------------------------
// Small GEMM: out = act(A[1024,512] @ Wt^T + bias). BM=64, BN=128,
// 256 thr = 4 waves (2Mx2N), wave 32x64. Two ops batched via blockIdx.y.
// act: 0=relu 1=tanh 2=none
// ---------------------------------------------------------------------------
__global__ __launch_bounds__(256) void gemm64(
        const float* __restrict__ A0, const unsigned short* __restrict__ W0,
        const float* __restrict__ bia0, float* __restrict__ O0, int act0,
        const float* __restrict__ A1, const unsigned short* __restrict__ W1,
        const float* __restrict__ bia1, float* __restrict__ O1, int act1) {
    const int op = blockIdx.y;
    const float* A = op ? A1 : A0;
    const unsigned short* Bt = op ? W1 : W0;
    const float* bias = op ? bia1 : bia0;
    float* out = op ? O1 : O0;
    const int act = op ? act1 : act0;

    __shared__ unsigned short A_lds[2][64 * 32];
    __shared__ unsigned short B_lds[2][128 * 32];

    const int tid = threadIdx.x;
    const int gm0 = (blockIdx.x >> 2) * 64, gn0 = (blockIdx.x & 3) * 128;
    const int wid = tid >> 6, lane = tid & 63;
    const int wm = wid >> 1, wn = wid & 1;
    const int lr = lane & 15, lk = lane >> 4;

    const int arow = tid >> 2, akc = tid & 3;
    const float* aptr = A + (size_t)(gm0 + arow) * KDIM + akc * 8;
    const int aoff = arow * 32 + ((akc ^ ((arow >> 1) & 3)) << 3);

    auto stageB = [&](int kt, int buf) {
#pragma unroll
        for (int j = 0; j < 2; ++j) {
            int c = tid + j * 256;
            int col = c >> 2, slot = c & 3;
            const unsigned short* src = Bt + (size_t)(gn0 + col) * KDIM +
                                        ((slot ^ ((col >> 1) & 3)) << 3) + kt * 32;
            gload16(src, &B_lds[buf][c * 8]);
        }
    };

    f32x4 acc[2][4] = {};

    {
        float4 x0 = *(const float4*)aptr;
        float4 x1 = *(const float4*)(aptr + 4);
        stageB(0, 0);
        uint4 p;
        p.x = pk2(x0.x, x0.y); p.y = pk2(x0.z, x0.w);
        p.z = pk2(x1.x, x1.y); p.w = pk2(x1.z, x1.w);
        *(uint4*)&A_lds[0][aoff] = p;
    }
    __syncthreads();

    const int swk = ((lk ^ ((lr >> 1) & 3)) << 3);
    for (int kt = 0; kt < 16; ++kt) {
        const int buf = kt & 1;
        float4 x0, x1;
        if (kt < 15) {
            const float* ap = aptr + (kt + 1) * 32;
            x0 = *(const float4*)ap;
            x1 = *(const float4*)(ap + 4);
            stageB(kt + 1, buf ^ 1);
        }
        bf16x8 af[2], bfr[4];
#pragma unroll
        for (int m = 0; m < 2; ++m)
            af[m] = *(const bf16x8*)&A_lds[buf][(wm * 32 + m * 16 + lr) * 32 + swk];
#pragma unroll
        for (int n = 0; n < 4; ++n)
            bfr[n] = *(const bf16x8*)&B_lds[buf][(wn * 64 + n * 16 + lr) * 32 + swk];
#pragma unroll
        for (int m = 0; m < 2; ++m)
#pragma unroll
            for (int n = 0; n < 4; ++n)
                acc[m][n] = __builtin_amdgcn_mfma_f32_16x16x32_bf16(af[m], bfr[n], acc[m][n], 0, 0, 0);
        if (kt < 15) {
            uint4 p;
            p.x = pk2(x0.x, x0.y); p.y = pk2(x0.z, x0.w);
            p.z = pk2(x1.x, x1.y); p.w = pk2(x1.z, x1.w);
            *(uint4*)&A_lds[buf ^ 1][aoff] = p;
        }
        __syncthreads();
    }

#pragma unroll
    for (int m = 0; m < 2; ++m)
#pragma unroll
        for (int n = 0; n < 4; ++n) {
            int col = gn0 + wn * 64 + n * 16 + lr;
            float bsv = bias[col];
#pragma unroll
            for (int r = 0; r < 4; ++r) {
                int row = gm0 + wm * 32 + m * 16 + lk * 4 + r;
                float v = acc[m][n][r] + bsv;
                if (act == 0) v = fmaxf(v, 0.f);
                else if (act == 1) v = fast_tanh(v);
                out[(size_t)row * NDIM + col] = v;
            }
        }
}

// ---------------------------------------------------------------------------
// Score GEMM (R14 structure, best measured ~290us): BM=256, BN=128, 512 thr
// (8 waves, 4Mx2N, wave 64x64). A reg-staged to bf16 LDS (T14: loads at loop
// top for t+1; cvt_pk + ds_write AFTER the MFMA cluster). Consumer reads A
// as bf16 directly. B via global_load_lds, source-baked swizzle.
// LDS 48 KB -> 2 blocks/CU. T5 setprio around the MFMA cluster.
// Epilogue handles up to 3 batch spans; atomicAdd partials into score.
// Grid 3136 = 8 XCD x 98 mtiles x 4 nblk.
// ---------------------------------------------------------------------------
__launch_bounds__(512, 4)
__global__ void gemm_score(const float* __restrict__ A,
                           const unsigned short* __restrict__ Bt,
                           const float* __restrict__ b_ctx,
                           const float* __restrict__ h_emb,
                           const float* __restrict__ Walpha,
                           float* __restrict__ score) {
    __shared__ char smem[49152];
    unsigned short (*A_lds)[256 * 32] = (unsigned short (*)[256 * 32])smem;          // 2x16KB bf16
    unsigned short (*B_lds)[128 * 32] = (unsigned short (*)[128 * 32])(smem + 32768); // 2x8KB
    // epilogue aliases (A_lds region dead after final barrier)
    float* ch_s = (float*)smem;            // [3][128]
    float* wa_s = (float*)(smem + 1536);   // [128]
    float* s_red = (float*)(smem + 2048);  // [2][256]

    const int tid  = threadIdx.x;
    const int bidx = blockIdx.x;
    const int xcd  = bidx & 7, u = bidx >> 3;
    const int mblk = xcd * 98 + (u >> 2), nblk = u & 3;
    const int gm0  = mblk * 256, gn0 = nblk * 128;

    const int wid = tid >> 6, lane = tid & 63;
    const int wm  = wid >> 1, wn = wid & 1;
    const int lr  = lane & 15, lk = lane >> 4;

    // A staging: thread -> row=tid>>1 (0..255), khalf=tid&1 (16 f32 = granules
    // 2a,2a+1). Granule g lands at slot g^((row>>1)&3) (R4-verified swizzle).
    const int arow = tid >> 1, ahalf = tid & 1;
    const float* aptr = A + (size_t)(gm0 + arow) * KDIM + ahalf * 16;
    const int skc0  = (ahalf * 2) ^ ((arow >> 1) & 3);
    const int aoff0 = arow * 32 + skc0 * 8;
    const int aoff1 = arow * 32 + (skc0 ^ 1) * 8;

    // B staging: chunk c=tid -> col=c>>2, slot=c&3 holds src kc=slot^((col>>1)&3)
    const int bcol = tid >> 2, bslot = tid & 3;
    const unsigned short* bsrc = Bt + (size_t)(gn0 + bcol) * KDIM +
                                 ((bslot ^ ((bcol >> 1) & 3)) << 3);
    auto stageB = [&](int kt, int buf) {
        gload16(bsrc + kt * 32, &B_lds[buf][tid * 8]);
    };
    auto writeA = [&](const float4& x0, const float4& x1,
                      const float4& x2, const float4& x3, int buf) {
        uint4 p0, p1;
        p0.x = pk2(x0.x, x0.y); p0.y = pk2(x0.z, x0.w);
        p0.z = pk2(x1.x, x1.y); p0.w = pk2(x1.z, x1.w);
        p1.x = pk2(x2.x, x2.y); p1.y = pk2(x2.z, x2.w);
        p1.z = pk2(x3.x, x3.y); p1.w = pk2(x3.z, x3.w);
        *(uint4*)&A_lds[buf][aoff0] = p0;
        *(uint4*)&A_lds[buf][aoff1] = p1;
    };

    f32x4 acc[4][4] = {};
    const int swk = ((lk ^ ((lr >> 1) & 3)) << 3);

    // prologue: stage tile 0
    {
        float4 x0 = *(const float4*)(aptr);
        float4 x1 = *(const float4*)(aptr + 4);
        float4 x2 = *(const float4*)(aptr + 8);
        float4 x3 = *(const float4*)(aptr + 12);
        stageB(0, 0);
        writeA(x0, x1, x2, x3, 0);
    }
    __syncthreads();

#pragma unroll 1
    for (int kt = 0; kt < 16; ++kt) {
        const int buf = kt & 1;
        float4 x0, x1, x2, x3;
        if (kt < 15) {
            const float* ap = aptr + (kt + 1) * 32;
            x0 = *(const float4*)(ap);
            x1 = *(const float4*)(ap + 4);
            x2 = *(const float4*)(ap + 8);
            x3 = *(const float4*)(ap + 12);
            stageB(kt + 1, buf ^ 1);
        }
        bf16x8 af[4], bfr[4];
#pragma unroll
        for (int n = 0; n < 4; ++n)
            bfr[n] = *(const bf16x8*)&B_lds[buf][(wn * 64 + n * 16 + lr) * 32 + swk];
#pragma unroll
        for (int m = 0; m < 4; ++m)
            af[m] = *(const bf16x8*)&A_lds[buf][(wm * 64 + m * 16 + lr) * 32 + swk];
        __builtin_amdgcn_s_setprio(1);
#pragma unroll
        for (int m = 0; m < 4; ++m)
#pragma unroll
            for (int n = 0; n < 4; ++n)
                acc[m][n] = __builtin_amdgcn_mfma_f32_16x16x32_bf16(af[m], bfr[n], acc[m][n], 0, 0, 0);
        __builtin_amdgcn_s_setprio(0);
        if (kt < 15) writeA(x0, x1, x2, x3, buf ^ 1);
        __syncthreads();
    }

    // ---- epilogue (A_lds/B_lds dead; aliased buffers live now) ----
    const int bb0 = gm0 / ATT;
    {
        int j = tid >> 7;                   // 0..3
        int c = tid & 127;
        if (j < 3) {
            int bb = bb0 + j; if (bb > NB - 1) bb = NB - 1;
            ch_s[j * 128 + c] = b_ctx[gn0 + c] + h_emb[(size_t)bb * NDIM + gn0 + c];
        }
        if (tid < 128) wa_s[tid] = Walpha[gn0 + tid];
    }
    __syncthreads();

#pragma unroll
    for (int m = 0; m < 4; ++m) {
#pragma unroll
        for (int r = 0; r < 4; ++r) {
            int rloc = wm * 64 + m * 16 + lk * 4 + r;     // 0..255
            int rg = gm0 + rloc;
            int sel = rg / ATT - bb0;                     // 0..2
            float sum = 0.f;
#pragma unroll
            for (int n = 0; n < 4; ++n) {
                int cloc = wn * 64 + n * 16 + lr;
                sum += fast_tanh(acc[m][n][r] + ch_s[sel * 128 + cloc]) * wa_s[cloc];
            }
            sum += __shfl_xor(sum, 1);
            sum += __shfl_xor(sum, 2);
            sum += __shfl_xor(sum, 4);
            sum += __shfl_xor(sum, 8);
            if (lr == 0) s_red[wn * 256 + rloc] = sum;
        }
    }
    __syncthreads();
    if (tid < 256) {
        float tot = s_red[tid] + s_red[256 + tid];
        int rg = gm0 + tid;
        int bb = rg / ATT;
        atomicAdd(&score[(size_t)bb * 197 + (rg - bb * ATT) + 1], tot);
    }
}

// ---------------------------------------------------------------------------
// Per-batch: sentinel score (pos 0) from sent_emb+h_emb, softmax over 197,
// atten_out[b,:] = al0*sent_lin + sum_s al[s+1]*att[b,s,:] + h_lin
// ---------------------------------------------------------------------------
__global__ __launch_bounds__(256) void softmax_chat(
        const float* __restrict__ score, const float* __restrict__ sent_emb,
        const float* __restrict__ h_emb, const float* __restrict__ Walpha,
        const float* __restrict__ sent_lin, const float* __restrict__ h_lin,
        const float* __restrict__ att, float* __restrict__ atten_out) {
    int b = blockIdx.x, tid = threadIdx.x;
    __shared__ float al[200];
    __shared__ float r4[4];

    float2 se = ((const float2*)(sent_emb + (size_t)b * NDIM))[tid];
    float2 he = ((const float2*)(h_emb + (size_t)b * NDIM))[tid];
    float2 wa = ((const float2*)Walpha)[tid];
    float val = fast_tanh(se.x + he.x) * wa.x + fast_tanh(se.y + he.y) * wa.y;
#pragma unroll
    for (int o = 32; o; o >>= 1) val += __shfl_xor(val, o);
    if ((tid & 63) == 0) r4[tid >> 6] = val;
    __syncthreads();
    float ssent = r4[0] + r4[1] + r4[2] + r4[3];
    __syncthreads();

    float v = -1e30f;
    if (tid < 197) v = (tid == 0) ? ssent : score[(size_t)b * 197 + tid];
    float m = v;
#pragma unroll
    for (int o = 32; o; o >>= 1) m = fmaxf(m, __shfl_xor(m, o));
    if ((tid & 63) == 0) r4[tid >> 6] = m;
    __syncthreads();
    m = fmaxf(fmaxf(r4[0], r4[1]), fmaxf(r4[2], r4[3]));
    __syncthreads();
    float e = (tid < 197) ? __expf(v - m) : 0.f;
    float s = e;
#pragma unroll
    for (int o = 32; o; o >>= 1) s += __shfl_xor(s, o);
    if ((tid & 63) == 0) r4[tid >> 6] = s;
    __syncthreads();
    s = r4[0] + r4[1] + r4[2] + r4[3];
    if (tid < 197) al[tid] = e / s;
    __syncthreads();

    const float2* af = (const float2*)(att + (size_t)b * ATT * KDIM);
    float2 a0 = ((const float2*)(sent_lin + (size_t)b * KDIM))[tid];
    float w0 = al[0];
    float2 accv; accv.x = w0 * a0.x; accv.y = w0 * a0.y;
#pragma unroll 14
    for (int ss = 0; ss < ATT; ++ss) {
        float w = al[ss + 1];
        float2 x = af[(size_t)ss * 256 + tid];
        accv.x += w * x.x; accv.y += w * x.y;
    }
    float2 hl = ((const float2*)(h_lin + (size_t)b * KDIM))[tid];
    accv.x += hl.x; accv.y += hl.y;
    ((float2*)(atten_out + (size_t)b * KDIM))[tid] = accv;
}

// ---------------------------------------------------------------------------
extern "C" void kernel_launch(void* const* d_in, const int* in_sizes, int n_in,
                              void* d_out, int out_size, void* d_ws, size_t ws_size,
                              hipStream_t stream) {
    const float* h     = (const float*)d_in[0];
    const float* sent  = (const float*)d_in[1];
    const float* att   = (const float*)d_in[2];
    const float* W_ctx = (const float*)d_in[3];
    const float* b_ctx = (const float*)d_in[4];
    const float* W_sl  = (const float*)d_in[5];
    const float* b_sl  = (const float*)d_in[6];
    const float* W_se  = (const float*)d_in[7];
    const float* b_se  = (const float*)d_in[8];
    const float* W_hl  = (const float*)d_in[9];
    const float* b_hl  = (const float*)d_in[10];
    const float* W_he  = (const float*)d_in[11];
    const float* b_he  = (const float*)d_in[12];
    const float* W_al  = (const float*)d_in[13];
    // d_in[14] = b_alpha: constant across positions, cancels in softmax
    const float* W_a2h = (const float*)d_in[15];
    const float* b_a2h = (const float*)d_in[16];
    float* out = (float*)d_out;

    char* ws = (char*)d_ws;
    unsigned short* Wt = (unsigned short*)ws;                 // 6 * 512KB bf16 = 3MB
    float* sent_lin = (float*)(ws + 6u * 512 * 1024);
    float* h_lin    = sent_lin + (size_t)NB * 512;
    float* h_emb    = h_lin    + (size_t)NB * 512;
    float* sent_emb = h_emb    + (size_t)NB * 512;
    float* scorebuf = sent_emb + (size_t)NB * 512;            // 1024*197
    float* atten    = scorebuf + (size_t)NB * 197;

    const size_t WSZ = 512 * 512;  // ushorts per weight
    // Wt order: 0=W_sl 1=W_hl 2=W_he 3=W_ctx 4=W_a2h 5=W_se
    // (also zeroes scorebuf — no separate memset launch)
    prep_weights<<<384, 256, 0, stream>>>(W_sl, W_hl, W_he, W_ctx, W_a2h, W_se,
                                          Wt, scorebuf);

    // sent_lin = relu(sent@W_sl+b_sl); h_lin = tanh(h@W_hl+b_hl)
    gemm64<<<dim3(64, 2), 256, 0, stream>>>(
        sent, Wt + 0 * WSZ, b_sl, sent_lin, 0,
        h,    Wt + 1 * WSZ, b_hl, h_lin,    1);
    // h_emb = h_lin@W_he+b_he; sent_emb = sent_lin@W_se+b_se
    gemm64<<<dim3(64, 2), 256, 0, stream>>>(
        h_lin,    Wt + 2 * WSZ, b_he, h_emb,    2,
        sent_lin, Wt + 5 * WSZ, b_se, sent_emb, 2);

    // visual scores -> scorebuf[b*197 + 1 + s]
    gemm_score<<<3136, 512, 0, stream>>>(att, Wt + 3 * WSZ, b_ctx, h_emb, W_al, scorebuf);

    softmax_chat<<<NB, 256, 0, stream>>>(scorebuf, sent_emb, h_emb, W_al,
                                         sent_lin, h_lin, att, atten);

    // out = tanh(atten@W_a2h + b_a2h)
    gemm64<<<dim3(64, 1), 256, 0, stream>>>(
        atten, Wt + 4 * WSZ, b_a2h, out, 1,
        atten, Wt + 4 * WSZ, b_a2h, out, 1);
}